// Round 1
// baseline (2281.373 us; speedup 1.0000x reference)
//
#include <hip/hip_runtime.h>

constexpr int IN_FEATS = 30;
constexpr int HIDDEN   = 64;

// ---- degrees: deg_out[src]++, deg_in[dst]++ (float, exact for small ints) ----
__global__ __launch_bounds__(256) void deg_kernel(
    const int* __restrict__ src, const int* __restrict__ dst,
    float* __restrict__ degO, float* __restrict__ degI, int nE)
{
    int i = blockIdx.x * blockDim.x + threadIdx.x;
    int stride = gridDim.x * blockDim.x;
    for (; i < nE; i += stride) {
        atomicAdd(&degO[src[i]], 1.0f);
        atomicAdd(&degI[dst[i]], 1.0f);
    }
}

// ---- norms in place: d = 1/sqrt(max(d,1)) ----
__global__ __launch_bounds__(256) void norm_kernel(
    float* __restrict__ degO, float* __restrict__ degI, int n)
{
    int i = blockIdx.x * blockDim.x + threadIdx.x;
    if (i < n) {
        degO[i] = 1.0f / sqrtf(fmaxf(degO[i], 1.0f));
        degI[i] = 1.0f / sqrtf(fmaxf(degI[i], 1.0f));
    }
}

// ---- layer-1 transform: out[node] = (x[node] * ns[node]) @ W1   [30 -> 64] ----
__global__ __launch_bounds__(256) void transform1(
    const float* __restrict__ x, const float* __restrict__ W1,
    const float* __restrict__ ns, float* __restrict__ out, int n)
{
    __shared__ float w[IN_FEATS * HIDDEN];   // 7.5 KB
    __shared__ float rows[4][IN_FEATS];
    for (int i = threadIdx.x; i < IN_FEATS * HIDDEN; i += 256) w[i] = W1[i];
    int grp  = threadIdx.x >> 6;
    int f    = threadIdx.x & 63;
    int node = blockIdx.x * 4 + grp;
    if (node < n && f < IN_FEATS) rows[grp][f] = x[node * IN_FEATS + f] * ns[node];
    __syncthreads();
    if (node < n) {
        float acc = 0.0f;
#pragma unroll
        for (int k = 0; k < IN_FEATS; ++k) acc = fmaf(rows[grp][k], w[k * HIDDEN + f], acc);
        out[node * HIDDEN + f] = acc;
    }
}

// ---- sparse aggregation: agg[dst] += h[src]; 16 lanes/edge, float4 gather ----
__global__ __launch_bounds__(256) void scatter_agg(
    const float* __restrict__ h, const int* __restrict__ src,
    const int* __restrict__ dst, float* __restrict__ agg, int nE)
{
    int tid = blockIdx.x * blockDim.x + threadIdx.x;
    int c = (tid & 15) * 4;
    int e = tid >> 4;
    int estride = (gridDim.x * blockDim.x) >> 4;
    for (; e < nE; e += estride) {
        int s = src[e], d = dst[e];
        float4 v = *reinterpret_cast<const float4*>(h + (size_t)s * HIDDEN + c);
        float* p = agg + (size_t)d * HIDDEN + c;
        atomicAdd(p + 0, v.x);
        atomicAdd(p + 1, v.y);
        atomicAdd(p + 2, v.z);
        atomicAdd(p + 3, v.w);
    }
}

// ---- layer-2 transform (fused with layer-1 epilogue):
//      out[node] = (relu(agg[node]*nd + b1) * ns) @ W2   [64 -> 64] ----
__global__ __launch_bounds__(256) void transform2(
    const float* __restrict__ agg, const float* __restrict__ W2,
    const float* __restrict__ b1, const float* __restrict__ ns,
    const float* __restrict__ nd, float* __restrict__ out, int n)
{
    __shared__ float w[HIDDEN * HIDDEN];     // 16 KB
    __shared__ float rows[4][HIDDEN];
    for (int i = threadIdx.x; i < HIDDEN * HIDDEN; i += 256) w[i] = W2[i];
    int grp  = threadIdx.x >> 6;
    int f    = threadIdx.x & 63;
    int node = blockIdx.x * 4 + grp;
    if (node < n) {
        float hv = fmaf(agg[node * HIDDEN + f], nd[node], b1[f]);
        hv = fmaxf(hv, 0.0f);
        rows[grp][f] = hv * ns[node];
    }
    __syncthreads();
    if (node < n) {
        float acc = 0.0f;
#pragma unroll
        for (int k = 0; k < HIDDEN; ++k) acc = fmaf(rows[grp][k], w[k * HIDDEN + f], acc);
        out[node * HIDDEN + f] = acc;
    }
}

// ---- final epilogue (in place on d_out): out = relu(agg*nd + b2) ----
// NOTE: agg/out intentionally NOT __restrict__ — called with agg == out.
__global__ __launch_bounds__(256) void post2(
    const float* agg, const float* __restrict__ b2,
    const float* __restrict__ nd, float* out, int n)
{
    int idx = blockIdx.x * blockDim.x + threadIdx.x;
    int stride = gridDim.x * blockDim.x;
    int total = n * (HIDDEN / 4);
    for (; idx < total; idx += stride) {
        int node = idx >> 4;
        int c = (idx & 15) * 4;
        float s = nd[node];
        float4 v = *reinterpret_cast<const float4*>(agg + (size_t)node * HIDDEN + c);
        float4 b = *reinterpret_cast<const float4*>(b2 + c);
        float4 r;
        r.x = fmaxf(fmaf(v.x, s, b.x), 0.0f);
        r.y = fmaxf(fmaf(v.y, s, b.y), 0.0f);
        r.z = fmaxf(fmaf(v.z, s, b.z), 0.0f);
        r.w = fmaxf(fmaf(v.w, s, b.w), 0.0f);
        *reinterpret_cast<float4*>(out + (size_t)node * HIDDEN + c) = r;
    }
}

extern "C" void kernel_launch(void* const* d_in, const int* in_sizes, int n_in,
                              void* d_out, int out_size, void* d_ws, size_t ws_size,
                              hipStream_t stream)
{
    const float* x  = (const float*)d_in[0];
    const float* W1 = (const float*)d_in[1];
    const float* b1 = (const float*)d_in[2];
    const float* W2 = (const float*)d_in[3];
    const float* b2 = (const float*)d_in[4];
    const int*  src = (const int*)d_in[5];
    const int*  dst = (const int*)d_in[6];
    float* out = (float*)d_out;

    const int n  = in_sizes[0] / IN_FEATS;   // 100000
    const int nE = in_sizes[5];              // 1200000

    // workspace layout: ns[n] | nd[n] | bufA[n*HIDDEN]   (= 26.4 MB total)
    float* ns   = (float*)d_ws;
    float* nd   = ns + n;
    float* bufA = nd + n;

    const size_t featBytes = (size_t)n * HIDDEN * sizeof(float);

    // degrees + norms
    hipMemsetAsync(ns, 0, (size_t)2 * n * sizeof(float), stream);
    deg_kernel<<<2048, 256, 0, stream>>>(src, dst, ns, nd, nE);
    norm_kernel<<<(n + 255) / 256, 256, 0, stream>>>(ns, nd, n);

    // layer 1: transform -> scatter-aggregate into d_out (used as scratch)
    transform1<<<(n + 3) / 4, 256, 0, stream>>>(x, W1, ns, bufA, n);
    hipMemsetAsync(out, 0, featBytes, stream);
    scatter_agg<<<2048, 256, 0, stream>>>(bufA, src, dst, out, nE);

    // layer 2: fused epilogue+transform -> scatter-aggregate -> final epilogue
    transform2<<<(n + 3) / 4, 256, 0, stream>>>(out, W2, b1, ns, nd, bufA, n);
    hipMemsetAsync(out, 0, featBytes, stream);
    scatter_agg<<<2048, 256, 0, stream>>>(bufA, src, dst, out, nE);
    post2<<<2048, 256, 0, stream>>>(out, b2, nd, out, n);
}

// Round 2
// 600.335 us; speedup vs baseline: 3.8002x; 3.8002x over previous
//
#include <hip/hip_runtime.h>

constexpr int IN_FEATS = 30;
constexpr int HIDDEN   = 64;

// ---- degree histograms (int) ----
__global__ __launch_bounds__(256) void hist_kernel(
    const int* __restrict__ src, const int* __restrict__ dst,
    int* __restrict__ degO, int* __restrict__ degI, int nE)
{
    int i = blockIdx.x * blockDim.x + threadIdx.x;
    int stride = gridDim.x * blockDim.x;
    for (; i < nE; i += stride) {
        atomicAdd(&degO[src[i]], 1);
        atomicAdd(&degI[dst[i]], 1);
    }
}

// ---- single-block exclusive scan of degI -> rowptr (start offsets) ----
#define SCAN_THREADS 1024
__global__ __launch_bounds__(SCAN_THREADS) void scan_kernel(
    const int* __restrict__ deg, int* __restrict__ rowptr, int n)
{
    __shared__ int part[SCAN_THREADS];
    int t = threadIdx.x;
    int chunk = (n + SCAN_THREADS - 1) / SCAN_THREADS;
    int begin = t * chunk;
    int end   = min(begin + chunk, n);
    int s = 0;
    for (int i = begin; i < end; ++i) s += deg[i];
    part[t] = s;
    __syncthreads();
    // Hillis-Steele inclusive scan over thread partials
    for (int off = 1; off < SCAN_THREADS; off <<= 1) {
        int add = (t >= off) ? part[t - off] : 0;
        __syncthreads();
        part[t] += add;
        __syncthreads();
    }
    int run = part[t] - s;   // exclusive prefix for this thread's chunk
    for (int i = begin; i < end; ++i) {
        rowptr[i] = run;
        run += deg[i];
    }
}

// ---- CSR fill: rowptr used as cursor; afterwards rowptr[i] == end offset of row i ----
__global__ __launch_bounds__(256) void fill_kernel(
    const int* __restrict__ src, const int* __restrict__ dst,
    int* __restrict__ rowptr, int* __restrict__ csr, int nE)
{
    int i = blockIdx.x * blockDim.x + threadIdx.x;
    int stride = gridDim.x * blockDim.x;
    for (; i < nE; i += stride) {
        int pos = atomicAdd(&rowptr[dst[i]], 1);
        csr[pos] = src[i];
    }
}

// ---- layer-1 aggregation: aggx[v] = sum_{u->v} x[u] * out_deg_norm(u)   [30 feats] ----
__global__ __launch_bounds__(256) void gather_x(
    const float* __restrict__ x, const int* __restrict__ csr,
    const int* __restrict__ rowptr, const int* __restrict__ degO,
    float* __restrict__ aggx, int n)
{
    int wv   = (blockIdx.x * 256 + threadIdx.x) >> 6;
    int lane = threadIdx.x & 63;
    if (wv >= n) return;
    int begin = wv ? rowptr[wv - 1] : 0;
    int end   = rowptr[wv];
    float acc = 0.0f, acc2 = 0.0f;
    int e = begin;
    for (; e + 1 < end; e += 2) {
        int s0 = csr[e], s1 = csr[e + 1];
        float n0 = rsqrtf(fmaxf((float)degO[s0], 1.0f));
        float n1 = rsqrtf(fmaxf((float)degO[s1], 1.0f));
        if (lane < IN_FEATS) {
            acc  = fmaf(x[(size_t)s0 * IN_FEATS + lane], n0, acc);
            acc2 = fmaf(x[(size_t)s1 * IN_FEATS + lane], n1, acc2);
        }
    }
    if (e < end) {
        int s0 = csr[e];
        float n0 = rsqrtf(fmaxf((float)degO[s0], 1.0f));
        if (lane < IN_FEATS) acc = fmaf(x[(size_t)s0 * IN_FEATS + lane], n0, acc);
    }
    if (lane < IN_FEATS) aggx[(size_t)wv * IN_FEATS + lane] = acc + acc2;
}

// ---- layer-1 dense: h1s[v] = relu((aggx[v] @ W1) * nd(v) + b1) * ns(v) ----
__global__ __launch_bounds__(256) void transform1(
    const float* __restrict__ aggx, const float* __restrict__ W1,
    const float* __restrict__ b1, const int* __restrict__ degI,
    const int* __restrict__ degO, float* __restrict__ out, int n)
{
    __shared__ float w[IN_FEATS * HIDDEN];   // 7.5 KB
    __shared__ float rows[4][IN_FEATS];
    for (int i = threadIdx.x; i < IN_FEATS * HIDDEN; i += 256) w[i] = W1[i];
    int g = threadIdx.x >> 6, f = threadIdx.x & 63;
    int node = blockIdx.x * 4 + g;
    if (node < n && f < IN_FEATS) rows[g][f] = aggx[(size_t)node * IN_FEATS + f];
    __syncthreads();
    if (node < n) {
        float acc = 0.0f;
#pragma unroll
        for (int k = 0; k < IN_FEATS; ++k) acc = fmaf(rows[g][k], w[k * HIDDEN + f], acc);
        float ndv = rsqrtf(fmaxf((float)degI[node], 1.0f));
        float nsv = rsqrtf(fmaxf((float)degO[node], 1.0f));
        float hv  = fmaxf(fmaf(acc, ndv, b1[f]), 0.0f);
        out[(size_t)node * HIDDEN + f] = hv * nsv;
    }
}

// ---- layer-2 aggregation: agg[v] = sum_{u->v} h1s[u]   [64 feats, 1 wave/node] ----
__global__ __launch_bounds__(256) void gather_h(
    const float* __restrict__ h, const int* __restrict__ csr,
    const int* __restrict__ rowptr, float* __restrict__ agg, int n)
{
    int wv   = (blockIdx.x * 256 + threadIdx.x) >> 6;
    int lane = threadIdx.x & 63;
    if (wv >= n) return;
    int begin = wv ? rowptr[wv - 1] : 0;
    int end   = rowptr[wv];
    float acc = 0.0f, acc2 = 0.0f;
    int e = begin;
    for (; e + 1 < end; e += 2) {
        int s0 = csr[e], s1 = csr[e + 1];
        acc  += h[(size_t)s0 * HIDDEN + lane];
        acc2 += h[(size_t)s1 * HIDDEN + lane];
    }
    if (e < end) acc += h[(size_t)csr[e] * HIDDEN + lane];
    agg[(size_t)wv * HIDDEN + lane] = acc + acc2;
}

// ---- layer-2 dense, in place on d_out: out[v] = relu((agg[v] @ W2) * nd(v) + b2) ----
// NOTE: agg == out (same buffer); block reads its rows before writing them.
__global__ __launch_bounds__(256) void transform2(
    float* aggout, const float* __restrict__ W2,
    const float* __restrict__ b2, const int* __restrict__ degI, int n)
{
    __shared__ float w[HIDDEN * HIDDEN];     // 16 KB
    __shared__ float rows[4][HIDDEN];
    for (int i = threadIdx.x; i < HIDDEN * HIDDEN; i += 256) w[i] = W2[i];
    int g = threadIdx.x >> 6, f = threadIdx.x & 63;
    int node = blockIdx.x * 4 + g;
    if (node < n) rows[g][f] = aggout[(size_t)node * HIDDEN + f];
    __syncthreads();
    if (node < n) {
        float acc = 0.0f;
#pragma unroll
        for (int k = 0; k < HIDDEN; ++k) acc = fmaf(rows[g][k], w[k * HIDDEN + f], acc);
        float ndv = rsqrtf(fmaxf((float)degI[node], 1.0f));
        aggout[(size_t)node * HIDDEN + f] = fmaxf(fmaf(acc, ndv, b2[f]), 0.0f);
    }
}

extern "C" void kernel_launch(void* const* d_in, const int* in_sizes, int n_in,
                              void* d_out, int out_size, void* d_ws, size_t ws_size,
                              hipStream_t stream)
{
    const float* x  = (const float*)d_in[0];
    const float* W1 = (const float*)d_in[1];
    const float* b1 = (const float*)d_in[2];
    const float* W2 = (const float*)d_in[3];
    const float* b2 = (const float*)d_in[4];
    const int*  src = (const int*)d_in[5];
    const int*  dst = (const int*)d_in[6];
    float* out = (float*)d_out;

    const int n  = in_sizes[0] / IN_FEATS;   // 100000
    const int nE = in_sizes[5];              // 1200000

    // workspace: degO[n] | degI[n] | rowptr[n] | csr[nE] | bufA[n*HIDDEN]  (~31.6 MB)
    int* degO   = (int*)d_ws;
    int* degI   = degO + n;
    int* rowptr = degI + n;
    int* csr    = rowptr + n;
    float* bufA = (float*)(csr + nE);

    const int waveBlocks = (n * 64 + 255) / 256;   // 1 wave per node
    const int tfBlocks   = (n + 3) / 4;            // 4 nodes per block

    // CSR build (by dst) + degrees
    hipMemsetAsync(degO, 0, (size_t)2 * n * sizeof(int), stream);
    hist_kernel<<<2048, 256, 0, stream>>>(src, dst, degO, degI, nE);
    scan_kernel<<<1, SCAN_THREADS, 0, stream>>>(degI, rowptr, n);
    fill_kernel<<<2048, 256, 0, stream>>>(src, dst, rowptr, csr, nE);
    // after fill, rowptr[i] == end offset of row i; begin = rowptr[i-1] (or 0)

    // layer 1: aggregate x*ns, then dense transform (+bias, relu, pre-scale by ns)
    gather_x<<<waveBlocks, 256, 0, stream>>>(x, csr, rowptr, degO, out /*aggx scratch*/, n);
    transform1<<<tfBlocks, 256, 0, stream>>>(out, W1, b1, degI, degO, bufA, n);

    // layer 2: aggregate h1s, then dense transform (+bias, relu) in place on d_out
    gather_h<<<waveBlocks, 256, 0, stream>>>(bufA, csr, rowptr, out, n);
    transform2<<<tfBlocks, 256, 0, stream>>>(out, W2, b2, degI, n);
}

// Round 3
// 451.343 us; speedup vs baseline: 5.0546x; 1.3301x over previous
//
#include <hip/hip_runtime.h>

constexpr int IN_FEATS = 30;
constexpr int HIDDEN   = 64;
constexpr int SCAN_CHUNK = 1024;   // elements per scan block (256 thr x 4)

// ---- degree histograms (int) ----
__global__ __launch_bounds__(256) void hist_kernel(
    const int* __restrict__ src, const int* __restrict__ dst,
    int* __restrict__ degO, int* __restrict__ degI, int nE)
{
    int i = blockIdx.x * blockDim.x + threadIdx.x;
    int stride = gridDim.x * blockDim.x;
    for (; i < nE; i += stride) {
        atomicAdd(&degO[src[i]], 1);
        atomicAdd(&degI[dst[i]], 1);
    }
}

// ---- multi-block exclusive scan, phase 1: per-block sums ----
__global__ __launch_bounds__(256) void scan_partial(
    const int* __restrict__ deg, int* __restrict__ blockSum, int n)
{
    __shared__ int part[256];
    int b = blockIdx.x, t = threadIdx.x;
    int base = b * SCAN_CHUNK + t * 4;
    int s = 0;
#pragma unroll
    for (int j = 0; j < 4; ++j) { int i = base + j; if (i < n) s += deg[i]; }
    part[t] = s;
    __syncthreads();
    for (int off = 1; off < 256; off <<= 1) {
        int add = (t >= off) ? part[t - off] : 0;
        __syncthreads();
        part[t] += add;
        __syncthreads();
    }
    if (t == 255) blockSum[b] = part[255];
}

// ---- phase 2: exclusive scan of block sums (1 block; nB <= 1024) ----
__global__ __launch_bounds__(1024) void scan_offsets(int* blockSum, int nB)
{
    __shared__ int part[1024];
    int t = threadIdx.x;
    int v = (t < nB) ? blockSum[t] : 0;
    part[t] = v;
    __syncthreads();
    for (int off = 1; off < 1024; off <<= 1) {
        int add = (t >= off) ? part[t - off] : 0;
        __syncthreads();
        part[t] += add;
        __syncthreads();
    }
    if (t < nB) blockSum[t] = part[t] - v;   // exclusive block offset
}

// ---- phase 3: rescan chunk, write exclusive start offsets ----
__global__ __launch_bounds__(256) void scan_final(
    const int* __restrict__ deg, const int* __restrict__ blockSum,
    int* __restrict__ rowptr, int n)
{
    __shared__ int part[256];
    int b = blockIdx.x, t = threadIdx.x;
    int base = b * SCAN_CHUNK + t * 4;
    int v[4];
    int s = 0;
#pragma unroll
    for (int j = 0; j < 4; ++j) { int i = base + j; v[j] = (i < n) ? deg[i] : 0; s += v[j]; }
    part[t] = s;
    __syncthreads();
    for (int off = 1; off < 256; off <<= 1) {
        int add = (t >= off) ? part[t - off] : 0;
        __syncthreads();
        part[t] += add;
        __syncthreads();
    }
    int run = blockSum[b] + part[t] - s;     // exclusive prefix for this thread
#pragma unroll
    for (int j = 0; j < 4; ++j) {
        int i = base + j;
        if (i < n) rowptr[i] = run;
        run += v[j];
    }
}

// ---- CSR fill: rowptr used as cursor; afterwards rowptr[i] == end offset of row i ----
__global__ __launch_bounds__(256) void fill_kernel(
    const int* __restrict__ src, const int* __restrict__ dst,
    int* __restrict__ rowptr, int* __restrict__ csr, int nE)
{
    int i = blockIdx.x * blockDim.x + threadIdx.x;
    int stride = gridDim.x * blockDim.x;
    for (; i < nE; i += stride) {
        int pos = atomicAdd(&rowptr[dst[i]], 1);
        csr[pos] = src[i];
    }
}

// ---- layer-1 aggregation: aggx[v] = sum_{u->v} x[u] * out_deg_norm(u)   [30 feats] ----
__global__ __launch_bounds__(256) void gather_x(
    const float* __restrict__ x, const int* __restrict__ csr,
    const int* __restrict__ rowptr, const int* __restrict__ degO,
    float* __restrict__ aggx, int n)
{
    int wv   = (blockIdx.x * 256 + threadIdx.x) >> 6;
    int lane = threadIdx.x & 63;
    if (wv >= n) return;
    int begin = wv ? rowptr[wv - 1] : 0;
    int end   = rowptr[wv];
    float acc = 0.0f, acc2 = 0.0f;
    int e = begin;
    for (; e + 1 < end; e += 2) {
        int s0 = csr[e], s1 = csr[e + 1];
        float n0 = rsqrtf(fmaxf((float)degO[s0], 1.0f));
        float n1 = rsqrtf(fmaxf((float)degO[s1], 1.0f));
        if (lane < IN_FEATS) {
            acc  = fmaf(x[(size_t)s0 * IN_FEATS + lane], n0, acc);
            acc2 = fmaf(x[(size_t)s1 * IN_FEATS + lane], n1, acc2);
        }
    }
    if (e < end) {
        int s0 = csr[e];
        float n0 = rsqrtf(fmaxf((float)degO[s0], 1.0f));
        if (lane < IN_FEATS) acc = fmaf(x[(size_t)s0 * IN_FEATS + lane], n0, acc);
    }
    if (lane < IN_FEATS) aggx[(size_t)wv * IN_FEATS + lane] = acc + acc2;
}

// ---- layer-1 dense: h1s[v] = relu((aggx[v] @ W1) * nd(v) + b1) * ns(v) ----
__global__ __launch_bounds__(256) void transform1(
    const float* __restrict__ aggx, const float* __restrict__ W1,
    const float* __restrict__ b1, const int* __restrict__ degI,
    const int* __restrict__ degO, float* __restrict__ out, int n)
{
    __shared__ float w[IN_FEATS * HIDDEN];   // 7.5 KB
    __shared__ float rows[4][IN_FEATS];
    for (int i = threadIdx.x; i < IN_FEATS * HIDDEN; i += 256) w[i] = W1[i];
    int g = threadIdx.x >> 6, f = threadIdx.x & 63;
    int node = blockIdx.x * 4 + g;
    if (node < n && f < IN_FEATS) rows[g][f] = aggx[(size_t)node * IN_FEATS + f];
    __syncthreads();
    if (node < n) {
        float acc = 0.0f;
#pragma unroll
        for (int k = 0; k < IN_FEATS; ++k) acc = fmaf(rows[g][k], w[k * HIDDEN + f], acc);
        float ndv = rsqrtf(fmaxf((float)degI[node], 1.0f));
        float nsv = rsqrtf(fmaxf((float)degO[node], 1.0f));
        float hv  = fmaxf(fmaf(acc, ndv, b1[f]), 0.0f);
        out[(size_t)node * HIDDEN + f] = hv * nsv;
    }
}

// ---- layer-2 aggregation: agg[v] = sum_{u->v} h1s[u]   [64 feats, 1 wave/node] ----
__global__ __launch_bounds__(256) void gather_h(
    const float* __restrict__ h, const int* __restrict__ csr,
    const int* __restrict__ rowptr, float* __restrict__ agg, int n)
{
    int wv   = (blockIdx.x * 256 + threadIdx.x) >> 6;
    int lane = threadIdx.x & 63;
    if (wv >= n) return;
    int begin = wv ? rowptr[wv - 1] : 0;
    int end   = rowptr[wv];
    float acc = 0.0f, acc2 = 0.0f;
    int e = begin;
    for (; e + 1 < end; e += 2) {
        int s0 = csr[e], s1 = csr[e + 1];
        acc  += h[(size_t)s0 * HIDDEN + lane];
        acc2 += h[(size_t)s1 * HIDDEN + lane];
    }
    if (e < end) acc += h[(size_t)csr[e] * HIDDEN + lane];
    agg[(size_t)wv * HIDDEN + lane] = acc + acc2;
}

// ---- layer-2 dense, in place on d_out: out[v] = relu((agg[v] @ W2) * nd(v) + b2) ----
// NOTE: agg == out (same buffer); block reads its rows before writing them.
__global__ __launch_bounds__(256) void transform2(
    float* aggout, const float* __restrict__ W2,
    const float* __restrict__ b2, const int* __restrict__ degI, int n)
{
    __shared__ float w[HIDDEN * HIDDEN];     // 16 KB
    __shared__ float rows[4][HIDDEN];
    for (int i = threadIdx.x; i < HIDDEN * HIDDEN; i += 256) w[i] = W2[i];
    int g = threadIdx.x >> 6, f = threadIdx.x & 63;
    int node = blockIdx.x * 4 + g;
    if (node < n) rows[g][f] = aggout[(size_t)node * HIDDEN + f];
    __syncthreads();
    if (node < n) {
        float acc = 0.0f;
#pragma unroll
        for (int k = 0; k < HIDDEN; ++k) acc = fmaf(rows[g][k], w[k * HIDDEN + f], acc);
        float ndv = rsqrtf(fmaxf((float)degI[node], 1.0f));
        aggout[(size_t)node * HIDDEN + f] = fmaxf(fmaf(acc, ndv, b2[f]), 0.0f);
    }
}

extern "C" void kernel_launch(void* const* d_in, const int* in_sizes, int n_in,
                              void* d_out, int out_size, void* d_ws, size_t ws_size,
                              hipStream_t stream)
{
    const float* x  = (const float*)d_in[0];
    const float* W1 = (const float*)d_in[1];
    const float* b1 = (const float*)d_in[2];
    const float* W2 = (const float*)d_in[3];
    const float* b2 = (const float*)d_in[4];
    const int*  src = (const int*)d_in[5];
    const int*  dst = (const int*)d_in[6];
    float* out = (float*)d_out;

    const int n  = in_sizes[0] / IN_FEATS;   // 100000
    const int nE = in_sizes[5];              // 1200000

    // workspace: degO[n] | degI[n] | rowptr[n] | csr[nE] | bufA[n*HIDDEN] | blockSum[nB]
    int* degO   = (int*)d_ws;
    int* degI   = degO + n;
    int* rowptr = degI + n;
    int* csr    = rowptr + n;
    float* bufA = (float*)(csr + nE);
    int* blockSum = (int*)(bufA + (size_t)n * HIDDEN);

    const int nB = (n + SCAN_CHUNK - 1) / SCAN_CHUNK;   // 98 scan blocks
    const int waveBlocks = (n * 64 + 255) / 256;        // 1 wave per node
    const int tfBlocks   = (n + 3) / 4;                 // 4 nodes per block

    // CSR build (by dst) + degrees
    hipMemsetAsync(degO, 0, (size_t)2 * n * sizeof(int), stream);
    hist_kernel<<<2048, 256, 0, stream>>>(src, dst, degO, degI, nE);
    scan_partial<<<nB, 256, 0, stream>>>(degI, blockSum, n);
    scan_offsets<<<1, 1024, 0, stream>>>(blockSum, nB);
    scan_final<<<nB, 256, 0, stream>>>(degI, blockSum, rowptr, n);
    fill_kernel<<<2048, 256, 0, stream>>>(src, dst, rowptr, csr, nE);
    // after fill, rowptr[i] == end offset of row i; begin = rowptr[i-1] (or 0)

    // layer 1: aggregate x*ns, then dense transform (+bias, relu, pre-scale by ns)
    gather_x<<<waveBlocks, 256, 0, stream>>>(x, csr, rowptr, degO, out /*aggx scratch*/, n);
    transform1<<<tfBlocks, 256, 0, stream>>>(out, W1, b1, degI, degO, bufA, n);

    // layer 2: aggregate h1s, then dense transform (+bias, relu) in place on d_out
    gather_h<<<waveBlocks, 256, 0, stream>>>(bufA, csr, rowptr, out, n);
    transform2<<<tfBlocks, 256, 0, stream>>>(out, W2, b2, degI, n);
}

// Round 4
// 401.079 us; speedup vs baseline: 5.6881x; 1.1253x over previous
//
#include <hip/hip_runtime.h>
#include <hip/hip_fp16.h>

constexpr int IN_FEATS = 30;
constexpr int HIDDEN   = 64;
constexpr int SCAN_CHUNK = 1024;   // elements per scan block (256 thr x 4)

// ---- degree histograms (int) ----
__global__ __launch_bounds__(256) void hist_kernel(
    const int* __restrict__ src, const int* __restrict__ dst,
    int* __restrict__ degO, int* __restrict__ degI, int nE)
{
    int i = blockIdx.x * blockDim.x + threadIdx.x;
    int stride = gridDim.x * blockDim.x;
    for (; i < nE; i += stride) {
        atomicAdd(&degO[src[i]], 1);
        atomicAdd(&degI[dst[i]], 1);
    }
}

// ---- multi-block exclusive scan, phase 1: per-block sums ----
__global__ __launch_bounds__(256) void scan_partial(
    const int* __restrict__ deg, int* __restrict__ blockSum, int n)
{
    __shared__ int part[256];
    int b = blockIdx.x, t = threadIdx.x;
    int base = b * SCAN_CHUNK + t * 4;
    int s = 0;
#pragma unroll
    for (int j = 0; j < 4; ++j) { int i = base + j; if (i < n) s += deg[i]; }
    part[t] = s;
    __syncthreads();
    for (int off = 1; off < 256; off <<= 1) {
        int add = (t >= off) ? part[t - off] : 0;
        __syncthreads();
        part[t] += add;
        __syncthreads();
    }
    if (t == 255) blockSum[b] = part[255];
}

// ---- phase 2: exclusive scan of block sums (1 block; nB <= 1024) ----
__global__ __launch_bounds__(1024) void scan_offsets(int* blockSum, int nB)
{
    __shared__ int part[1024];
    int t = threadIdx.x;
    int v = (t < nB) ? blockSum[t] : 0;
    part[t] = v;
    __syncthreads();
    for (int off = 1; off < 1024; off <<= 1) {
        int add = (t >= off) ? part[t - off] : 0;
        __syncthreads();
        part[t] += add;
        __syncthreads();
    }
    if (t < nB) blockSum[t] = part[t] - v;   // exclusive block offset
}

// ---- phase 3: rescan chunk, write exclusive start offsets ----
__global__ __launch_bounds__(256) void scan_final(
    const int* __restrict__ deg, const int* __restrict__ blockSum,
    int* __restrict__ rowptr, int n)
{
    __shared__ int part[256];
    int b = blockIdx.x, t = threadIdx.x;
    int base = b * SCAN_CHUNK + t * 4;
    int v[4];
    int s = 0;
#pragma unroll
    for (int j = 0; j < 4; ++j) { int i = base + j; v[j] = (i < n) ? deg[i] : 0; s += v[j]; }
    part[t] = s;
    __syncthreads();
    for (int off = 1; off < 256; off <<= 1) {
        int add = (t >= off) ? part[t - off] : 0;
        __syncthreads();
        part[t] += add;
        __syncthreads();
    }
    int run = blockSum[b] + part[t] - s;     // exclusive prefix for this thread
#pragma unroll
    for (int j = 0; j < 4; ++j) {
        int i = base + j;
        if (i < n) rowptr[i] = run;
        run += v[j];
    }
}

// ---- CSR fill: rowptr used as cursor; afterwards rowptr[i] == end offset of row i ----
__global__ __launch_bounds__(256) void fill_kernel(
    const int* __restrict__ src, const int* __restrict__ dst,
    int* __restrict__ rowptr, int* __restrict__ csr, int nE)
{
    int i = blockIdx.x * blockDim.x + threadIdx.x;
    int stride = gridDim.x * blockDim.x;
    for (; i < nE; i += stride) {
        int pos = atomicAdd(&rowptr[dst[i]], 1);
        csr[pos] = src[i];
    }
}

// ---- precompute xn[u] = fp16(x[u] * out_deg_norm(u)), padded 30->32 feats ----
__global__ __launch_bounds__(256) void xn_prep(
    const float* __restrict__ x, const int* __restrict__ degO,
    unsigned int* __restrict__ xn, int n)
{
    int tid = blockIdx.x * 256 + threadIdx.x;
    int node = tid >> 4, p = tid & 15;
    if (node >= n) return;
    float ns = rsqrtf(fmaxf((float)degO[node], 1.0f));
    float a = (2 * p     < IN_FEATS) ? x[(size_t)node * IN_FEATS + 2 * p]     * ns : 0.0f;
    float b = (2 * p + 1 < IN_FEATS) ? x[(size_t)node * IN_FEATS + 2 * p + 1] * ns : 0.0f;
    __half2 h = __floats2half2_rn(a, b);
    xn[(size_t)node * 16 + p] = *reinterpret_cast<unsigned int*>(&h);
}

// ---- layer-1 aggregation: aggx[v] = sum_{u->v} xn[u]; 4 edges/wave, 64 B/edge ----
__global__ __launch_bounds__(256) void gather_x2(
    const unsigned int* __restrict__ xn, const int* __restrict__ csr,
    const int* __restrict__ rowptr, float* __restrict__ aggx, int n)
{
    int wv   = (blockIdx.x * 256 + threadIdx.x) >> 6;
    int lane = threadIdx.x & 63;
    if (wv >= n) return;
    int begin = wv ? rowptr[wv - 1] : 0;
    int end   = rowptr[wv];
    int g = lane >> 4;        // edge slot 0..3
    int p = lane & 15;        // feature pair 0..15
    float accx = 0.0f, accy = 0.0f;
    for (int e = begin; e + g < end; e += 4) {
        int s = csr[e + g];
        unsigned int u = xn[(size_t)s * 16 + p];
        __half2 h = *reinterpret_cast<__half2*>(&u);
        float2 v = __half22float2(h);
        accx += v.x; accy += v.y;
    }
    accx += __shfl_xor(accx, 16); accy += __shfl_xor(accy, 16);
    accx += __shfl_xor(accx, 32); accy += __shfl_xor(accy, 32);
    if (g == 0) {
        float2 r = make_float2(accx, accy);
        *reinterpret_cast<float2*>(aggx + (size_t)wv * 32 + 2 * p) = r;
    }
}

// ---- layer-1 dense: h1s[v] = fp16(relu((aggx[v] @ W1) * nd + b1) * ns), packed x2 ----
__global__ __launch_bounds__(256) void transform1(
    const float* __restrict__ aggx, const float* __restrict__ W1,
    const float* __restrict__ b1, const int* __restrict__ degI,
    const int* __restrict__ degO, unsigned int* __restrict__ h1s, int n)
{
    __shared__ float w[32 * HIDDEN];     // 8 KB, rows 30..31 zeroed
    __shared__ float rows[4][32];
    for (int i = threadIdx.x; i < 32 * HIDDEN; i += 256)
        w[i] = (i < IN_FEATS * HIDDEN) ? W1[i] : 0.0f;
    int g = threadIdx.x >> 6, f = threadIdx.x & 63;
    int node = blockIdx.x * 4 + g;
    if (node < n && f < 32) rows[g][f] = aggx[(size_t)node * 32 + f];
    __syncthreads();
    float acc = 0.0f;
#pragma unroll
    for (int k = 0; k < 32; ++k) acc = fmaf(rows[g][k], w[k * HIDDEN + f], acc);
    float hv = 0.0f;
    if (node < n) {
        float ndv = rsqrtf(fmaxf((float)degI[node], 1.0f));
        float nsv = rsqrtf(fmaxf((float)degO[node], 1.0f));
        hv = fmaxf(fmaf(acc, ndv, b1[f]), 0.0f) * nsv;
    }
    float hv1 = __shfl_down(hv, 1);      // lane f gets lane f+1's value
    if (node < n && (f & 1) == 0) {
        __half2 h = __floats2half2_rn(hv, hv1);
        h1s[(size_t)node * 32 + (f >> 1)] = *reinterpret_cast<unsigned int*>(&h);
    }
}

// ---- layer-2 aggregation: agg[v] = sum_{u->v} h1s[u]; 2 edges/wave, 128 B/edge ----
__global__ __launch_bounds__(256) void gather_h2(
    const unsigned int* __restrict__ h, const int* __restrict__ csr,
    const int* __restrict__ rowptr, float* __restrict__ agg, int n)
{
    int wv   = (blockIdx.x * 256 + threadIdx.x) >> 6;
    int lane = threadIdx.x & 63;
    if (wv >= n) return;
    int begin = wv ? rowptr[wv - 1] : 0;
    int end   = rowptr[wv];
    int g = lane >> 5;        // edge slot 0..1
    int p = lane & 31;        // feature pair 0..31
    float accx = 0.0f, accy = 0.0f;
    for (int e = begin; e + g < end; e += 2) {
        int s = csr[e + g];
        unsigned int u = h[(size_t)s * 32 + p];
        __half2 hh = *reinterpret_cast<__half2*>(&u);
        float2 v = __half22float2(hh);
        accx += v.x; accy += v.y;
    }
    accx += __shfl_xor(accx, 32); accy += __shfl_xor(accy, 32);
    if (g == 0) {
        float2 r = make_float2(accx, accy);
        *reinterpret_cast<float2*>(agg + (size_t)wv * 64 + 2 * p) = r;
    }
}

// ---- layer-2 dense, in place on d_out: out[v] = relu((agg[v] @ W2) * nd + b2) ----
// NOTE: aggout aliased (agg == out); block reads its rows before writing them.
__global__ __launch_bounds__(256) void transform2(
    float* aggout, const float* __restrict__ W2,
    const float* __restrict__ b2, const int* __restrict__ degI, int n)
{
    __shared__ float w[HIDDEN * HIDDEN];     // 16 KB
    __shared__ float rows[4][HIDDEN];
    for (int i = threadIdx.x; i < HIDDEN * HIDDEN; i += 256) w[i] = W2[i];
    int g = threadIdx.x >> 6, f = threadIdx.x & 63;
    int node = blockIdx.x * 4 + g;
    if (node < n) rows[g][f] = aggout[(size_t)node * HIDDEN + f];
    __syncthreads();
    if (node < n) {
        float acc = 0.0f;
#pragma unroll
        for (int k = 0; k < HIDDEN; ++k) acc = fmaf(rows[g][k], w[k * HIDDEN + f], acc);
        float ndv = rsqrtf(fmaxf((float)degI[node], 1.0f));
        aggout[(size_t)node * HIDDEN + f] = fmaxf(fmaf(acc, ndv, b2[f]), 0.0f);
    }
}

extern "C" void kernel_launch(void* const* d_in, const int* in_sizes, int n_in,
                              void* d_out, int out_size, void* d_ws, size_t ws_size,
                              hipStream_t stream)
{
    const float* x  = (const float*)d_in[0];
    const float* W1 = (const float*)d_in[1];
    const float* b1 = (const float*)d_in[2];
    const float* W2 = (const float*)d_in[3];
    const float* b2 = (const float*)d_in[4];
    const int*  src = (const int*)d_in[5];
    const int*  dst = (const int*)d_in[6];
    float* out = (float*)d_out;

    const int n  = in_sizes[0] / IN_FEATS;   // 100000
    const int nE = in_sizes[5];              // 1200000

    // workspace: degO[n] | degI[n] | rowptr[n] | csr[nE] | xn[n*16] | h1s[n*32] | blockSum
    int* degO   = (int*)d_ws;
    int* degI   = degO + n;
    int* rowptr = degI + n;
    int* csr    = rowptr + n;
    unsigned int* xn  = (unsigned int*)(csr + nE);
    unsigned int* h1s = xn + (size_t)n * 16;
    int* blockSum = (int*)(h1s + (size_t)n * 32);

    const int nB = (n + SCAN_CHUNK - 1) / SCAN_CHUNK;   // 98 scan blocks
    const int waveBlocks = (n * 64 + 255) / 256;        // 1 wave per node
    const int tfBlocks   = (n + 3) / 4;                 // 4 nodes per block

    // CSR build (by dst) + degrees
    hipMemsetAsync(degO, 0, (size_t)2 * n * sizeof(int), stream);
    hist_kernel<<<2048, 256, 0, stream>>>(src, dst, degO, degI, nE);
    scan_partial<<<nB, 256, 0, stream>>>(degI, blockSum, n);
    scan_offsets<<<1, 1024, 0, stream>>>(blockSum, nB);
    scan_final<<<nB, 256, 0, stream>>>(degI, blockSum, rowptr, n);
    fill_kernel<<<2048, 256, 0, stream>>>(src, dst, rowptr, csr, nE);
    // after fill, rowptr[i] == end offset of row i; begin = rowptr[i-1] (or 0)

    // layer 1: pack x*ns to fp16, aggregate (into d_out scratch), dense transform
    xn_prep<<<(n * 16 + 255) / 256, 256, 0, stream>>>(x, degO, xn, n);
    gather_x2<<<waveBlocks, 256, 0, stream>>>(xn, csr, rowptr, out /*aggx*/, n);
    transform1<<<tfBlocks, 256, 0, stream>>>(out, W1, b1, degI, degO, h1s, n);

    // layer 2: aggregate h1s (fp16 lines) into d_out, dense transform in place
    gather_h2<<<waveBlocks, 256, 0, stream>>>(h1s, csr, rowptr, out, n);
    transform2<<<tfBlocks, 256, 0, stream>>>(out, W2, b2, degI, n);
}

// Round 5
// 325.903 us; speedup vs baseline: 7.0002x; 1.2307x over previous
//
#include <hip/hip_runtime.h>
#include <hip/hip_fp16.h>

constexpr int IN_FEATS = 30;
constexpr int HIDDEN   = 64;
constexpr int SCAN_CHUNK = 1024;   // elements per scan block (256 thr x 4)
constexpr int RB_BITS = 9;         // 512 nodes per bucket
constexpr int ECHUNK  = 2048;      // edges per partition block

// ---- degO histogram (global atomics; ~25 Gatomic/s floor) ----
__global__ __launch_bounds__(256) void hist_degO(
    const int* __restrict__ src, int* __restrict__ degO, int nE)
{
    int i = blockIdx.x * blockDim.x + threadIdx.x;
    int stride = gridDim.x * blockDim.x;
    int n4 = nE >> 2;
    const int4* s4 = (const int4*)src;
    for (int j = i; j < n4; j += stride) {
        int4 v = s4[j];
        atomicAdd(&degO[v.x], 1); atomicAdd(&degO[v.y], 1);
        atomicAdd(&degO[v.z], 1); atomicAdd(&degO[v.w], 1);
    }
    for (int j = (n4 << 2) + i; j < nE; j += stride) atomicAdd(&degO[src[j]], 1);
}

// ---- partition pass 1: per-chunk LDS bucket histogram -> cntT[k*NCH + b] ----
__global__ __launch_bounds__(256) void part_count(
    const int* __restrict__ dst, int* __restrict__ cntT, int nE, int NBK, int NCH)
{
    __shared__ int bins[256];
    int b = blockIdx.x, t = threadIdx.x;
    bins[t] = 0;
    __syncthreads();
    int base = b * ECHUNK;
#pragma unroll
    for (int i = 0; i < ECHUNK / 256; ++i) {
        int e = base + t + i * 256;
        if (e < nE) atomicAdd(&bins[dst[e] >> RB_BITS], 1);
    }
    __syncthreads();
    if (t < NBK) cntT[t * NCH + b] = bins[t];
}

// ---- multi-block exclusive scan, phase 1: per-block sums ----
__global__ __launch_bounds__(256) void scan_partial(
    const int* __restrict__ deg, int* __restrict__ blockSum, int n)
{
    __shared__ int part[256];
    int b = blockIdx.x, t = threadIdx.x;
    int base = b * SCAN_CHUNK + t * 4;
    int s = 0;
#pragma unroll
    for (int j = 0; j < 4; ++j) { int i = base + j; if (i < n) s += deg[i]; }
    part[t] = s;
    __syncthreads();
    for (int off = 1; off < 256; off <<= 1) {
        int add = (t >= off) ? part[t - off] : 0;
        __syncthreads();
        part[t] += add;
        __syncthreads();
    }
    if (t == 255) blockSum[b] = part[255];
}

// ---- phase 2: exclusive scan of block sums (1 block; nB <= 1024); optional total ----
__global__ __launch_bounds__(1024) void scan_offsets(int* blockSum, int nB, int* totalPtr)
{
    __shared__ int part[1024];
    int t = threadIdx.x;
    int v = (t < nB) ? blockSum[t] : 0;
    part[t] = v;
    __syncthreads();
    for (int off = 1; off < 1024; off <<= 1) {
        int add = (t >= off) ? part[t - off] : 0;
        __syncthreads();
        part[t] += add;
        __syncthreads();
    }
    if (t < nB) blockSum[t] = part[t] - v;   // exclusive block offset
    if (totalPtr && t == nB - 1) *totalPtr = part[t];
}

// ---- phase 3: rescan chunk, write exclusive start offsets ----
__global__ __launch_bounds__(256) void scan_final(
    const int* __restrict__ deg, const int* __restrict__ blockSum,
    int* __restrict__ outp, int n)
{
    __shared__ int part[256];
    int b = blockIdx.x, t = threadIdx.x;
    int base = b * SCAN_CHUNK + t * 4;
    int v[4];
    int s = 0;
#pragma unroll
    for (int j = 0; j < 4; ++j) { int i = base + j; v[j] = (i < n) ? deg[i] : 0; s += v[j]; }
    part[t] = s;
    __syncthreads();
    for (int off = 1; off < 256; off <<= 1) {
        int add = (t >= off) ? part[t - off] : 0;
        __syncthreads();
        part[t] += add;
        __syncthreads();
    }
    int run = blockSum[b] + part[t] - s;
#pragma unroll
    for (int j = 0; j < 4; ++j) {
        int i = base + j;
        if (i < n) outp[i] = run;
        run += v[j];
    }
}

// ---- partition pass 2: local counting sort in LDS, bucket-contiguous pair write ----
__global__ __launch_bounds__(256) void part_scatter(
    const int* __restrict__ src, const int* __restrict__ dst,
    const int* __restrict__ ofsT, int* __restrict__ psrc, int* __restrict__ pdst,
    int nE, int NBK, int NCH)
{
    __shared__ int bins[256], lstart[256], lcur[256], gofs[256], part[256];
    __shared__ int lsrc[ECHUNK], ldst[ECHUNK];
    int b = blockIdx.x, t = threadIdx.x;
    bins[t] = 0;
    if (t < NBK) gofs[t] = ofsT[t * NCH + b];
    __syncthreads();
    int base = b * ECHUNK;
    int rs[ECHUNK / 256], rd[ECHUNK / 256];
#pragma unroll
    for (int i = 0; i < ECHUNK / 256; ++i) {
        int e = base + t + i * 256;
        rs[i] = -1;
        if (e < nE) {
            rs[i] = src[e]; rd[i] = dst[e];
            atomicAdd(&bins[rd[i] >> RB_BITS], 1);
        }
    }
    __syncthreads();
    int v = bins[t];
    part[t] = v;
    __syncthreads();
    for (int off = 1; off < 256; off <<= 1) {
        int add = (t >= off) ? part[t - off] : 0;
        __syncthreads();
        part[t] += add;
        __syncthreads();
    }
    lstart[t] = part[t] - v;
    lcur[t]   = part[t] - v;
    __syncthreads();
#pragma unroll
    for (int i = 0; i < ECHUNK / 256; ++i) {
        if (rs[i] >= 0) {
            int k = rd[i] >> RB_BITS;
            int p = atomicAdd(&lcur[k], 1);
            lsrc[p] = rs[i]; ldst[p] = rd[i];
        }
    }
    __syncthreads();
    int cE = min(ECHUNK, nE - base);
    for (int j = t; j < cE; j += 256) {
        int d = ldst[j], k = d >> RB_BITS;
        int g = gofs[k] + (j - lstart[k]);
        psrc[g] = lsrc[j];
        pdst[g] = d;
    }
}

// ---- per-bucket degI histogram in LDS (zero global atomics) ----
__global__ __launch_bounds__(256) void bucket_hist(
    const int* __restrict__ pdst, const int* __restrict__ ofsT,
    int* __restrict__ degI, int nE, int n, int NBK, int NCH)
{
    __shared__ int bins[512];
    int k = blockIdx.x, t = threadIdx.x;
    bins[t] = 0; bins[t + 256] = 0;
    __syncthreads();
    int begin = ofsT[k * NCH];
    int end   = (k + 1 < NBK) ? ofsT[(k + 1) * NCH] : nE;
    int base  = k << RB_BITS;
    for (int e = begin + t; e < end; e += 256)
        atomicAdd(&bins[pdst[e] - base], 1);
    __syncthreads();
    int node = base + t;
    if (node < n) degI[node] = bins[t];
    node += 256;
    if (node < n) degI[node] = bins[t + 256];
}

// ---- per-bucket csr placement: LDS cursors, scatter stays L2-resident ----
__global__ __launch_bounds__(256) void csr_place(
    const int* __restrict__ psrc, const int* __restrict__ pdst,
    const int* __restrict__ ofsT, const int* __restrict__ rowptr,
    int* __restrict__ csr, int nE, int n, int NBK, int NCH)
{
    __shared__ int cur[512];
    int k = blockIdx.x, t = threadIdx.x;
    int base = k << RB_BITS;
    int node = base + t;
    cur[t] = (node < n) ? rowptr[node] : 0;
    node += 256;
    cur[t + 256] = (node < n) ? rowptr[node] : 0;
    __syncthreads();
    int begin = ofsT[k * NCH];
    int end   = (k + 1 < NBK) ? ofsT[(k + 1) * NCH] : nE;
    for (int e = begin + t; e < end; e += 256) {
        int d = pdst[e];
        int p = atomicAdd(&cur[d - base], 1);
        csr[p] = psrc[e];
    }
}

// ---- precompute xn[u] = fp16(x[u] * out_deg_norm(u)), padded 30->32 feats ----
__global__ __launch_bounds__(256) void xn_prep(
    const float* __restrict__ x, const int* __restrict__ degO,
    unsigned int* __restrict__ xn, int n)
{
    int tid = blockIdx.x * 256 + threadIdx.x;
    int node = tid >> 4, p = tid & 15;
    if (node >= n) return;
    float ns = rsqrtf(fmaxf((float)degO[node], 1.0f));
    float a = (2 * p     < IN_FEATS) ? x[(size_t)node * IN_FEATS + 2 * p]     * ns : 0.0f;
    float b = (2 * p + 1 < IN_FEATS) ? x[(size_t)node * IN_FEATS + 2 * p + 1] * ns : 0.0f;
    __half2 h = __floats2half2_rn(a, b);
    xn[(size_t)node * 16 + p] = *reinterpret_cast<unsigned int*>(&h);
}

// ---- layer-1 aggregation: aggx[v] = sum_{u->v} xn[u]; 4 edges/wave, 64 B/edge ----
__global__ __launch_bounds__(256) void gather_x2(
    const unsigned int* __restrict__ xn, const int* __restrict__ csr,
    const int* __restrict__ rowptr, float* __restrict__ aggx, int n)
{
    int wv   = (blockIdx.x * 256 + threadIdx.x) >> 6;
    int lane = threadIdx.x & 63;
    if (wv >= n) return;
    int begin = rowptr[wv];
    int end   = rowptr[wv + 1];
    int g = lane >> 4;        // edge slot 0..3
    int p = lane & 15;        // feature pair 0..15
    float accx = 0.0f, accy = 0.0f;
    for (int e = begin; e + g < end; e += 4) {
        int s = csr[e + g];
        unsigned int u = xn[(size_t)s * 16 + p];
        __half2 h = *reinterpret_cast<__half2*>(&u);
        float2 v = __half22float2(h);
        accx += v.x; accy += v.y;
    }
    accx += __shfl_xor(accx, 16); accy += __shfl_xor(accy, 16);
    accx += __shfl_xor(accx, 32); accy += __shfl_xor(accy, 32);
    if (g == 0) {
        float2 r = make_float2(accx, accy);
        *reinterpret_cast<float2*>(aggx + (size_t)wv * 32 + 2 * p) = r;
    }
}

// ---- layer-1 dense: h1s[v] = fp16(relu((aggx[v] @ W1) * nd + b1) * ns), packed x2 ----
__global__ __launch_bounds__(256) void transform1(
    const float* __restrict__ aggx, const float* __restrict__ W1,
    const float* __restrict__ b1, const int* __restrict__ degI,
    const int* __restrict__ degO, unsigned int* __restrict__ h1s, int n)
{
    __shared__ float w[32 * HIDDEN];
    __shared__ float rows[4][32];
    for (int i = threadIdx.x; i < 32 * HIDDEN; i += 256)
        w[i] = (i < IN_FEATS * HIDDEN) ? W1[i] : 0.0f;
    int g = threadIdx.x >> 6, f = threadIdx.x & 63;
    int node = blockIdx.x * 4 + g;
    if (node < n && f < 32) rows[g][f] = aggx[(size_t)node * 32 + f];
    __syncthreads();
    float acc = 0.0f;
#pragma unroll
    for (int k = 0; k < 32; ++k) acc = fmaf(rows[g][k], w[k * HIDDEN + f], acc);
    float hv = 0.0f;
    if (node < n) {
        float ndv = rsqrtf(fmaxf((float)degI[node], 1.0f));
        float nsv = rsqrtf(fmaxf((float)degO[node], 1.0f));
        hv = fmaxf(fmaf(acc, ndv, b1[f]), 0.0f) * nsv;
    }
    float hv1 = __shfl_down(hv, 1);
    if (node < n && (f & 1) == 0) {
        __half2 h = __floats2half2_rn(hv, hv1);
        h1s[(size_t)node * 32 + (f >> 1)] = *reinterpret_cast<unsigned int*>(&h);
    }
}

// ---- layer-2 aggregation: agg[v] = sum_{u->v} h1s[u]; 2 edges/wave, 128 B/edge ----
__global__ __launch_bounds__(256) void gather_h2(
    const unsigned int* __restrict__ h, const int* __restrict__ csr,
    const int* __restrict__ rowptr, float* __restrict__ agg, int n)
{
    int wv   = (blockIdx.x * 256 + threadIdx.x) >> 6;
    int lane = threadIdx.x & 63;
    if (wv >= n) return;
    int begin = rowptr[wv];
    int end   = rowptr[wv + 1];
    int g = lane >> 5;        // edge slot 0..1
    int p = lane & 31;        // feature pair 0..31
    float accx = 0.0f, accy = 0.0f;
    for (int e = begin; e + g < end; e += 2) {
        int s = csr[e + g];
        unsigned int u = h[(size_t)s * 32 + p];
        __half2 hh = *reinterpret_cast<__half2*>(&u);
        float2 v = __half22float2(hh);
        accx += v.x; accy += v.y;
    }
    accx += __shfl_xor(accx, 32); accy += __shfl_xor(accy, 32);
    if (g == 0) {
        float2 r = make_float2(accx, accy);
        *reinterpret_cast<float2*>(agg + (size_t)wv * 64 + 2 * p) = r;
    }
}

// ---- layer-2 dense, in place on d_out: out[v] = relu((agg[v] @ W2) * nd + b2) ----
__global__ __launch_bounds__(256) void transform2(
    float* aggout, const float* __restrict__ W2,
    const float* __restrict__ b2, const int* __restrict__ degI, int n)
{
    __shared__ float w[HIDDEN * HIDDEN];
    __shared__ float rows[4][HIDDEN];
    for (int i = threadIdx.x; i < HIDDEN * HIDDEN; i += 256) w[i] = W2[i];
    int g = threadIdx.x >> 6, f = threadIdx.x & 63;
    int node = blockIdx.x * 4 + g;
    if (node < n) rows[g][f] = aggout[(size_t)node * HIDDEN + f];
    __syncthreads();
    if (node < n) {
        float acc = 0.0f;
#pragma unroll
        for (int k = 0; k < HIDDEN; ++k) acc = fmaf(rows[g][k], w[k * HIDDEN + f], acc);
        float ndv = rsqrtf(fmaxf((float)degI[node], 1.0f));
        aggout[(size_t)node * HIDDEN + f] = fmaxf(fmaf(acc, ndv, b2[f]), 0.0f);
    }
}

extern "C" void kernel_launch(void* const* d_in, const int* in_sizes, int n_in,
                              void* d_out, int out_size, void* d_ws, size_t ws_size,
                              hipStream_t stream)
{
    const float* x  = (const float*)d_in[0];
    const float* W1 = (const float*)d_in[1];
    const float* b1 = (const float*)d_in[2];
    const float* W2 = (const float*)d_in[3];
    const float* b2 = (const float*)d_in[4];
    const int*  src = (const int*)d_in[5];
    const int*  dst = (const int*)d_in[6];
    float* out = (float*)d_out;

    const int n  = in_sizes[0] / IN_FEATS;   // 100000
    const int nE = in_sizes[5];              // 1200000

    const int NBK = (n + (1 << RB_BITS) - 1) >> RB_BITS;     // 196 buckets (<=256)
    const int NCH = (nE + ECHUNK - 1) / ECHUNK;              // 586 chunks
    const int NK2 = NBK * NCH;                               // counts matrix size

    // workspace (words): degO[n] | degI[n] | rowptr[n+1] | csr[nE] |
    //   A: { cntT[NK2] | ofsT[NK2] | bsum[1024] | psrc[nE] | pdst[nE] }
    //   A reused later: xn (n*16 u32) then h1s (n*32 u32), both dead-time disjoint.
    int* degO   = (int*)d_ws;
    int* degI   = degO + n;
    int* rowptr = degI + n;
    int* csr    = rowptr + (n + 1);
    int* cntT   = csr + nE;
    int* ofsT   = cntT + NK2;
    int* bsum   = ofsT + NK2;
    int* psrc   = bsum + 1024;
    int* pdst   = psrc + nE;
    unsigned int* xn  = (unsigned int*)cntT;   // alive steps 9-10 (pairs dead)
    unsigned int* h1s = (unsigned int*)cntT;   // alive steps 11-12 (xn dead)

    const int nB  = (n + SCAN_CHUNK - 1) / SCAN_CHUNK;       // degI scan blocks
    const int nB2 = (NK2 + SCAN_CHUNK - 1) / SCAN_CHUNK;     // cntT scan blocks
    const int waveBlocks = (n * 64 + 255) / 256;
    const int tfBlocks   = (n + 3) / 4;

    // degO histogram (only remaining global-atomic hist)
    hipMemsetAsync(degO, 0, (size_t)n * sizeof(int), stream);
    hist_degO<<<1024, 256, 0, stream>>>(src, degO, nE);

    // bucketed CSR build (by dst): count -> scan -> scatter pairs -> hist -> scan -> place
    part_count<<<NCH, 256, 0, stream>>>(dst, cntT, nE, NBK, NCH);
    scan_partial<<<nB2, 256, 0, stream>>>(cntT, bsum, NK2);
    scan_offsets<<<1, 1024, 0, stream>>>(bsum, nB2, nullptr);
    scan_final<<<nB2, 256, 0, stream>>>(cntT, bsum, ofsT, NK2);
    part_scatter<<<NCH, 256, 0, stream>>>(src, dst, ofsT, psrc, pdst, nE, NBK, NCH);
    bucket_hist<<<NBK, 256, 0, stream>>>(pdst, ofsT, degI, nE, n, NBK, NCH);
    scan_partial<<<nB, 256, 0, stream>>>(degI, bsum, n);
    scan_offsets<<<1, 1024, 0, stream>>>(bsum, nB, rowptr + n);   // rowptr[n] = nE
    scan_final<<<nB, 256, 0, stream>>>(degI, bsum, rowptr, n);
    csr_place<<<NBK, 256, 0, stream>>>(psrc, pdst, ofsT, rowptr, csr, nE, n, NBK, NCH);

    // layer 1: pack x*ns to fp16, aggregate (into d_out scratch), dense transform
    xn_prep<<<(n * 16 + 255) / 256, 256, 0, stream>>>(x, degO, xn, n);
    gather_x2<<<waveBlocks, 256, 0, stream>>>(xn, csr, rowptr, out /*aggx*/, n);
    transform1<<<tfBlocks, 256, 0, stream>>>(out, W1, b1, degI, degO, h1s, n);

    // layer 2: aggregate h1s (fp16 lines) into d_out, dense transform in place
    gather_h2<<<waveBlocks, 256, 0, stream>>>(h1s, csr, rowptr, out, n);
    transform2<<<tfBlocks, 256, 0, stream>>>(out, W2, b2, degI, n);
}

// Round 6
// 240.990 us; speedup vs baseline: 9.4667x; 1.3524x over previous
//
#include <hip/hip_runtime.h>
#include <hip/hip_fp16.h>

constexpr int IN_FEATS = 30;
constexpr int HIDDEN   = 64;
constexpr int SCAN_CHUNK = 1024;   // elements per scan block (256 thr x 4)
constexpr int RB_BITS = 9;         // 512 nodes per bucket
constexpr int RB_MASK = (1 << RB_BITS) - 1;
constexpr int ECHUNK  = 2048;      // edges per partition block
// pair packing: (dstLocal << 23) | src  — requires n < 2^23 (here n = 100000)

// ---- partition pass 1: per-chunk LDS bucket histograms for BOTH dst and src ----
// cntT layout: [0..NK2)        = dst counts, row k col b
//              [NK2..2*NK2)    = src counts
__global__ __launch_bounds__(256) void part_count(
    const int* __restrict__ src, const int* __restrict__ dst,
    int* __restrict__ cntT, int nE, int NBK, int NCH, int NK2)
{
    __shared__ int binsD[256], binsS[256];
    int b = blockIdx.x, t = threadIdx.x;
    binsD[t] = 0; binsS[t] = 0;
    __syncthreads();
    int base = b * ECHUNK;
#pragma unroll
    for (int i = 0; i < ECHUNK / 256; ++i) {
        int e = base + t + i * 256;
        if (e < nE) {
            atomicAdd(&binsD[dst[e] >> RB_BITS], 1);
            atomicAdd(&binsS[src[e] >> RB_BITS], 1);
        }
    }
    __syncthreads();
    if (t < NBK) {
        cntT[t * NCH + b]       = binsD[t];
        cntT[NK2 + t * NCH + b] = binsS[t];
    }
}

// ---- multi-block exclusive scan, phase 1: per-block sums ----
__global__ __launch_bounds__(256) void scan_partial(
    const int* __restrict__ deg, int* __restrict__ blockSum, int n)
{
    __shared__ int part[256];
    int b = blockIdx.x, t = threadIdx.x;
    int base = b * SCAN_CHUNK + t * 4;
    int s = 0;
#pragma unroll
    for (int j = 0; j < 4; ++j) { int i = base + j; if (i < n) s += deg[i]; }
    part[t] = s;
    __syncthreads();
    for (int off = 1; off < 256; off <<= 1) {
        int add = (t >= off) ? part[t - off] : 0;
        __syncthreads();
        part[t] += add;
        __syncthreads();
    }
    if (t == 255) blockSum[b] = part[255];
}

// ---- phase 2: exclusive scan of block sums (1 block; nB <= 1024); optional total ----
__global__ __launch_bounds__(1024) void scan_offsets(int* blockSum, int nB, int* totalPtr)
{
    __shared__ int part[1024];
    int t = threadIdx.x;
    int v = (t < nB) ? blockSum[t] : 0;
    part[t] = v;
    __syncthreads();
    for (int off = 1; off < 1024; off <<= 1) {
        int add = (t >= off) ? part[t - off] : 0;
        __syncthreads();
        part[t] += add;
        __syncthreads();
    }
    if (t < nB) blockSum[t] = part[t] - v;   // exclusive block offset
    if (totalPtr && t == nB - 1) *totalPtr = part[t];
}

// ---- phase 3: rescan chunk, write exclusive start offsets ----
__global__ __launch_bounds__(256) void scan_final(
    const int* __restrict__ deg, const int* __restrict__ blockSum,
    int* __restrict__ outp, int n)
{
    __shared__ int part[256];
    int b = blockIdx.x, t = threadIdx.x;
    int base = b * SCAN_CHUNK + t * 4;
    int v[4];
    int s = 0;
#pragma unroll
    for (int j = 0; j < 4; ++j) { int i = base + j; v[j] = (i < n) ? deg[i] : 0; s += v[j]; }
    part[t] = s;
    __syncthreads();
    for (int off = 1; off < 256; off <<= 1) {
        int add = (t >= off) ? part[t - off] : 0;
        __syncthreads();
        part[t] += add;
        __syncthreads();
    }
    int run = blockSum[b] + part[t] - s;
#pragma unroll
    for (int j = 0; j < 4; ++j) {
        int i = base + j;
        if (i < n) outp[i] = run;
        run += v[j];
    }
}

// ---- dst partition pass 2: LDS counting sort, packed-pair bucket-contiguous write ----
__global__ __launch_bounds__(256) void part_scatter(
    const int* __restrict__ src, const int* __restrict__ dst,
    const int* __restrict__ ofsT, unsigned int* __restrict__ pairs,
    int nE, int NBK, int NCH)
{
    __shared__ int bins[256], lstart[256], lcur[256], gofs[256], part[256];
    __shared__ int lsrc[ECHUNK], ldst[ECHUNK];
    int b = blockIdx.x, t = threadIdx.x;
    bins[t] = 0;
    if (t < NBK) gofs[t] = ofsT[t * NCH + b];
    __syncthreads();
    int base = b * ECHUNK;
    int rs[ECHUNK / 256], rd[ECHUNK / 256];
#pragma unroll
    for (int i = 0; i < ECHUNK / 256; ++i) {
        int e = base + t + i * 256;
        rs[i] = -1;
        if (e < nE) {
            rs[i] = src[e]; rd[i] = dst[e];
            atomicAdd(&bins[rd[i] >> RB_BITS], 1);
        }
    }
    __syncthreads();
    int v = bins[t];
    part[t] = v;
    __syncthreads();
    for (int off = 1; off < 256; off <<= 1) {
        int add = (t >= off) ? part[t - off] : 0;
        __syncthreads();
        part[t] += add;
        __syncthreads();
    }
    lstart[t] = part[t] - v;
    lcur[t]   = part[t] - v;
    __syncthreads();
#pragma unroll
    for (int i = 0; i < ECHUNK / 256; ++i) {
        if (rs[i] >= 0) {
            int k = rd[i] >> RB_BITS;
            int p = atomicAdd(&lcur[k], 1);
            lsrc[p] = rs[i]; ldst[p] = rd[i];
        }
    }
    __syncthreads();
    int cE = min(ECHUNK, nE - base);
    for (int j = t; j < cE; j += 256) {
        int d = ldst[j], k = d >> RB_BITS;
        int g = gofs[k] + (j - lstart[k]);
        pairs[g] = ((unsigned int)(d & RB_MASK) << 23) | (unsigned int)lsrc[j];
    }
}

// ---- src partition scatter (no sort needed): 16-bit local ids, LDS cursors ----
__global__ __launch_bounds__(256) void srcpart_scatter(
    const int* __restrict__ src, const int* __restrict__ ofsT,
    unsigned short* __restrict__ sloc, int nE, int NBK, int NCH, int NK2)
{
    __shared__ int cur[256];
    int b = blockIdx.x, t = threadIdx.x;
    if (t < NBK) cur[t] = ofsT[NK2 + t * NCH + b] - nE;   // src offsets live at [nE..2nE)
    __syncthreads();
    int base = b * ECHUNK;
#pragma unroll
    for (int i = 0; i < ECHUNK / 256; ++i) {
        int e = base + t + i * 256;
        if (e < nE) {
            int s = src[e];
            int pos = atomicAdd(&cur[s >> RB_BITS], 1);
            sloc[pos] = (unsigned short)(s & RB_MASK);
        }
    }
}

// ---- per-bucket degI histogram from packed pairs (zero global atomics) ----
__global__ __launch_bounds__(256) void bucket_histD(
    const unsigned int* __restrict__ pairs, const int* __restrict__ ofsT,
    int* __restrict__ degI, int nE, int n, int NBK, int NCH)
{
    __shared__ int bins[512];
    int k = blockIdx.x, t = threadIdx.x;
    bins[t] = 0; bins[t + 256] = 0;
    __syncthreads();
    int begin = ofsT[k * NCH];
    int end   = (k + 1 < NBK) ? ofsT[(k + 1) * NCH] : nE;
    for (int e = begin + t; e < end; e += 256)
        atomicAdd(&bins[pairs[e] >> 23], 1);
    __syncthreads();
    int base = k << RB_BITS;
    if (base + t < n)       degI[base + t]       = bins[t];
    if (base + 256 + t < n) degI[base + 256 + t] = bins[t + 256];
}

// ---- per-bucket degO histogram from src local ids ----
__global__ __launch_bounds__(256) void bucket_histS(
    const unsigned short* __restrict__ sloc, const int* __restrict__ ofsT,
    int* __restrict__ degO, int nE, int n, int NBK, int NCH, int NK2)
{
    __shared__ int bins[512];
    int k = blockIdx.x, t = threadIdx.x;
    bins[t] = 0; bins[t + 256] = 0;
    __syncthreads();
    int begin = ofsT[NK2 + k * NCH] - nE;
    int end   = (k + 1 < NBK) ? (ofsT[NK2 + (k + 1) * NCH] - nE) : nE;
    for (int e = begin + t; e < end; e += 256)
        atomicAdd(&bins[sloc[e]], 1);
    __syncthreads();
    int base = k << RB_BITS;
    if (base + t < n)       degO[base + t]       = bins[t];
    if (base + 256 + t < n) degO[base + 256 + t] = bins[t + 256];
}

// ---- per-bucket csr placement: LDS cursors, scatter stays L2-resident ----
__global__ __launch_bounds__(256) void csr_place(
    const unsigned int* __restrict__ pairs, const int* __restrict__ ofsT,
    const int* __restrict__ rowptr, int* __restrict__ csr,
    int nE, int n, int NBK, int NCH)
{
    __shared__ int cur[512];
    int k = blockIdx.x, t = threadIdx.x;
    int base = k << RB_BITS;
    int node = base + t;
    cur[t] = (node < n) ? rowptr[node] : 0;
    node += 256;
    cur[t + 256] = (node < n) ? rowptr[node] : 0;
    __syncthreads();
    int begin = ofsT[k * NCH];
    int end   = (k + 1 < NBK) ? ofsT[(k + 1) * NCH] : nE;
    for (int e = begin + t; e < end; e += 256) {
        unsigned int u = pairs[e];
        int p = atomicAdd(&cur[u >> 23], 1);
        csr[p] = (int)(u & 0x7FFFFFu);
    }
}

// ---- precompute xn[u] = fp16(x[u] * out_deg_norm(u)), padded 30->32 feats ----
__global__ __launch_bounds__(256) void xn_prep(
    const float* __restrict__ x, const int* __restrict__ degO,
    unsigned int* __restrict__ xn, int n)
{
    int tid = blockIdx.x * 256 + threadIdx.x;
    int node = tid >> 4, p = tid & 15;
    if (node >= n) return;
    float ns = rsqrtf(fmaxf((float)degO[node], 1.0f));
    float a = (2 * p     < IN_FEATS) ? x[(size_t)node * IN_FEATS + 2 * p]     * ns : 0.0f;
    float b = (2 * p + 1 < IN_FEATS) ? x[(size_t)node * IN_FEATS + 2 * p + 1] * ns : 0.0f;
    __half2 h = __floats2half2_rn(a, b);
    xn[(size_t)node * 16 + p] = *reinterpret_cast<unsigned int*>(&h);
}

// ---- layer-1 aggregation: 8 edge slots/wave, uint2 loads, 2x unroll ----
__global__ __launch_bounds__(256) void gather_x2(
    const unsigned int* __restrict__ xn, const int* __restrict__ csr,
    const int* __restrict__ rowptr, float* __restrict__ aggx, int n)
{
    int wv   = (blockIdx.x * 256 + threadIdx.x) >> 6;
    int lane = threadIdx.x & 63;
    if (wv >= n) return;
    int begin = rowptr[wv], end = rowptr[wv + 1];
    int g = lane >> 3;        // edge slot 0..7
    int p = lane & 7;         // uint2 index (feats 4p..4p+3)
    float a0 = 0, a1 = 0, a2 = 0, a3 = 0;
    int e = begin + g;
    for (; e + 8 < end; e += 16) {
        int s0 = csr[e], s1 = csr[e + 8];
        uint2 u0 = *reinterpret_cast<const uint2*>(xn + (size_t)s0 * 16 + 2 * p);
        uint2 u1 = *reinterpret_cast<const uint2*>(xn + (size_t)s1 * 16 + 2 * p);
        float2 v;
        v = __half22float2(*reinterpret_cast<__half2*>(&u0.x)); a0 += v.x; a1 += v.y;
        v = __half22float2(*reinterpret_cast<__half2*>(&u0.y)); a2 += v.x; a3 += v.y;
        v = __half22float2(*reinterpret_cast<__half2*>(&u1.x)); a0 += v.x; a1 += v.y;
        v = __half22float2(*reinterpret_cast<__half2*>(&u1.y)); a2 += v.x; a3 += v.y;
    }
    if (e < end) {
        int s0 = csr[e];
        uint2 u0 = *reinterpret_cast<const uint2*>(xn + (size_t)s0 * 16 + 2 * p);
        float2 v;
        v = __half22float2(*reinterpret_cast<__half2*>(&u0.x)); a0 += v.x; a1 += v.y;
        v = __half22float2(*reinterpret_cast<__half2*>(&u0.y)); a2 += v.x; a3 += v.y;
    }
    a0 += __shfl_xor(a0, 8);  a1 += __shfl_xor(a1, 8);  a2 += __shfl_xor(a2, 8);  a3 += __shfl_xor(a3, 8);
    a0 += __shfl_xor(a0, 16); a1 += __shfl_xor(a1, 16); a2 += __shfl_xor(a2, 16); a3 += __shfl_xor(a3, 16);
    a0 += __shfl_xor(a0, 32); a1 += __shfl_xor(a1, 32); a2 += __shfl_xor(a2, 32); a3 += __shfl_xor(a3, 32);
    if (g == 0) {
        float4 r = make_float4(a0, a1, a2, a3);
        *reinterpret_cast<float4*>(aggx + (size_t)wv * 32 + 4 * p) = r;
    }
}

// ---- layer-1 dense: h1s[v] = fp16(relu((aggx[v] @ W1) * nd + b1) * ns), packed x2 ----
__global__ __launch_bounds__(256) void transform1(
    const float* __restrict__ aggx, const float* __restrict__ W1,
    const float* __restrict__ b1, const int* __restrict__ degI,
    const int* __restrict__ degO, unsigned int* __restrict__ h1s, int n)
{
    __shared__ float w[32 * HIDDEN];
    __shared__ float rows[4][32];
    for (int i = threadIdx.x; i < 32 * HIDDEN; i += 256)
        w[i] = (i < IN_FEATS * HIDDEN) ? W1[i] : 0.0f;
    int g = threadIdx.x >> 6, f = threadIdx.x & 63;
    int node = blockIdx.x * 4 + g;
    if (node < n && f < 32) rows[g][f] = aggx[(size_t)node * 32 + f];
    __syncthreads();
    float acc = 0.0f;
#pragma unroll
    for (int k = 0; k < 32; ++k) acc = fmaf(rows[g][k], w[k * HIDDEN + f], acc);
    float hv = 0.0f;
    if (node < n) {
        float ndv = rsqrtf(fmaxf((float)degI[node], 1.0f));
        float nsv = rsqrtf(fmaxf((float)degO[node], 1.0f));
        hv = fmaxf(fmaf(acc, ndv, b1[f]), 0.0f) * nsv;
    }
    float hv1 = __shfl_down(hv, 1);
    if (node < n && (f & 1) == 0) {
        __half2 h = __floats2half2_rn(hv, hv1);
        h1s[(size_t)node * 32 + (f >> 1)] = *reinterpret_cast<unsigned int*>(&h);
    }
}

// ---- layer-2 aggregation: 4 edge slots/wave, uint2 loads, 2x unroll ----
__global__ __launch_bounds__(256) void gather_h2(
    const unsigned int* __restrict__ h, const int* __restrict__ csr,
    const int* __restrict__ rowptr, float* __restrict__ agg, int n)
{
    int wv   = (blockIdx.x * 256 + threadIdx.x) >> 6;
    int lane = threadIdx.x & 63;
    if (wv >= n) return;
    int begin = rowptr[wv], end = rowptr[wv + 1];
    int g = lane >> 4;        // edge slot 0..3
    int p = lane & 15;        // uint2 index (feats 4p..4p+3)
    float a0 = 0, a1 = 0, a2 = 0, a3 = 0;
    int e = begin + g;
    for (; e + 4 < end; e += 8) {
        int s0 = csr[e], s1 = csr[e + 4];
        uint2 u0 = *reinterpret_cast<const uint2*>(h + (size_t)s0 * 32 + 2 * p);
        uint2 u1 = *reinterpret_cast<const uint2*>(h + (size_t)s1 * 32 + 2 * p);
        float2 v;
        v = __half22float2(*reinterpret_cast<__half2*>(&u0.x)); a0 += v.x; a1 += v.y;
        v = __half22float2(*reinterpret_cast<__half2*>(&u0.y)); a2 += v.x; a3 += v.y;
        v = __half22float2(*reinterpret_cast<__half2*>(&u1.x)); a0 += v.x; a1 += v.y;
        v = __half22float2(*reinterpret_cast<__half2*>(&u1.y)); a2 += v.x; a3 += v.y;
    }
    if (e < end) {
        int s0 = csr[e];
        uint2 u0 = *reinterpret_cast<const uint2*>(h + (size_t)s0 * 32 + 2 * p);
        float2 v;
        v = __half22float2(*reinterpret_cast<__half2*>(&u0.x)); a0 += v.x; a1 += v.y;
        v = __half22float2(*reinterpret_cast<__half2*>(&u0.y)); a2 += v.x; a3 += v.y;
    }
    a0 += __shfl_xor(a0, 16); a1 += __shfl_xor(a1, 16); a2 += __shfl_xor(a2, 16); a3 += __shfl_xor(a3, 16);
    a0 += __shfl_xor(a0, 32); a1 += __shfl_xor(a1, 32); a2 += __shfl_xor(a2, 32); a3 += __shfl_xor(a3, 32);
    if (g == 0) {
        float4 r = make_float4(a0, a1, a2, a3);
        *reinterpret_cast<float4*>(agg + (size_t)wv * 64 + 4 * p) = r;
    }
}

// ---- layer-2 dense, in place on d_out: out[v] = relu((agg[v] @ W2) * nd + b2) ----
__global__ __launch_bounds__(256) void transform2(
    float* aggout, const float* __restrict__ W2,
    const float* __restrict__ b2, const int* __restrict__ degI, int n)
{
    __shared__ float w[HIDDEN * HIDDEN];
    __shared__ float rows[4][HIDDEN];
    for (int i = threadIdx.x; i < HIDDEN * HIDDEN; i += 256) w[i] = W2[i];
    int g = threadIdx.x >> 6, f = threadIdx.x & 63;
    int node = blockIdx.x * 4 + g;
    if (node < n) rows[g][f] = aggout[(size_t)node * HIDDEN + f];
    __syncthreads();
    if (node < n) {
        float acc = 0.0f;
#pragma unroll
        for (int k = 0; k < HIDDEN; ++k) acc = fmaf(rows[g][k], w[k * HIDDEN + f], acc);
        float ndv = rsqrtf(fmaxf((float)degI[node], 1.0f));
        aggout[(size_t)node * HIDDEN + f] = fmaxf(fmaf(acc, ndv, b2[f]), 0.0f);
    }
}

extern "C" void kernel_launch(void* const* d_in, const int* in_sizes, int n_in,
                              void* d_out, int out_size, void* d_ws, size_t ws_size,
                              hipStream_t stream)
{
    const float* x  = (const float*)d_in[0];
    const float* W1 = (const float*)d_in[1];
    const float* b1 = (const float*)d_in[2];
    const float* W2 = (const float*)d_in[3];
    const float* b2 = (const float*)d_in[4];
    const int*  src = (const int*)d_in[5];
    const int*  dst = (const int*)d_in[6];
    float* out = (float*)d_out;

    const int n  = in_sizes[0] / IN_FEATS;   // 100000
    const int nE = in_sizes[5];              // 1200000

    const int NBK = (n + (1 << RB_BITS) - 1) >> RB_BITS;     // 196 buckets (<=256)
    const int NCH = (nE + ECHUNK - 1) / ECHUNK;              // 586 chunks
    const int NK2 = NBK * NCH;

    // workspace: pool FIRST (16B-aligned base) so uint2/float4 loads are aligned.
    //   pool phase A: pairs[nE] | cntT[2*NK2] | bsum[1024] | sloc[nE u16]
    //   pool phase B: xn[n*16 u32] then h1s[n*32 u32]   (phase-A arrays dead)
    // persistent after pool: degO[n] | degI[n] | rowptr[n+1] | csr[nE]
    // total = n*32 + 3n+1 + nE words = 18.8 MB (same proven footprint as round 5)
    const size_t poolWords = (size_t)n * 32;
    unsigned int* pairs = (unsigned int*)d_ws;
    int* cntT = (int*)d_ws + nE;
    int* bsum = cntT + 2 * NK2;
    unsigned short* sloc = (unsigned short*)(bsum + 1024);
    unsigned int* xn  = (unsigned int*)d_ws;
    unsigned int* h1s = (unsigned int*)d_ws;
    int* degO   = (int*)d_ws + poolWords;
    int* degI   = degO + n;
    int* rowptr = degI + n;
    int* csr    = rowptr + (n + 1);

    const int nB  = (n + SCAN_CHUNK - 1) / SCAN_CHUNK;           // degI scan blocks
    const int nB2 = (2 * NK2 + SCAN_CHUNK - 1) / SCAN_CHUNK;     // combined cntT scan
    const int waveBlocks = (n * 64 + 255) / 256;
    const int tfBlocks   = (n + 3) / 4;

    // combined dst+src bucket counts -> one scan over 2*NK2
    part_count<<<NCH, 256, 0, stream>>>(src, dst, cntT, nE, NBK, NCH, NK2);
    scan_partial<<<nB2, 256, 0, stream>>>(cntT, bsum, 2 * NK2);
    scan_offsets<<<1, 1024, 0, stream>>>(bsum, nB2, nullptr);
    scan_final<<<nB2, 256, 0, stream>>>(cntT, bsum, cntT, 2 * NK2);   // in-place offsets

    // dst partition -> packed pairs; src partition -> 16-bit local ids
    part_scatter<<<NCH, 256, 0, stream>>>(src, dst, cntT, pairs, nE, NBK, NCH);
    srcpart_scatter<<<NCH, 256, 0, stream>>>(src, cntT, sloc, nE, NBK, NCH, NK2);

    // per-bucket LDS histograms (zero global atomics, no memsets needed)
    bucket_histD<<<NBK, 256, 0, stream>>>(pairs, cntT, degI, nE, n, NBK, NCH);
    bucket_histS<<<NBK, 256, 0, stream>>>(sloc, cntT, degO, nE, n, NBK, NCH, NK2);

    // rowptr = exclusive scan of degI; rowptr[n] = nE
    scan_partial<<<nB, 256, 0, stream>>>(degI, bsum, n);
    scan_offsets<<<1, 1024, 0, stream>>>(bsum, nB, rowptr + n);
    scan_final<<<nB, 256, 0, stream>>>(degI, bsum, rowptr, n);
    csr_place<<<NBK, 256, 0, stream>>>(pairs, cntT, rowptr, csr, nE, n, NBK, NCH);

    // layer 1: pack x*ns to fp16 (pool reuse), aggregate into d_out, dense transform
    xn_prep<<<(n * 16 + 255) / 256, 256, 0, stream>>>(x, degO, xn, n);
    gather_x2<<<waveBlocks, 256, 0, stream>>>(xn, csr, rowptr, out /*aggx*/, n);
    transform1<<<tfBlocks, 256, 0, stream>>>(out, W1, b1, degI, degO, h1s, n);

    // layer 2: aggregate h1s into d_out, dense transform in place
    gather_h2<<<waveBlocks, 256, 0, stream>>>(h1s, csr, rowptr, out, n);
    transform2<<<tfBlocks, 256, 0, stream>>>(out, W2, b2, degI, n);
}

// Round 7
// 196.510 us; speedup vs baseline: 11.6094x; 1.2263x over previous
//
#include <hip/hip_runtime.h>
#include <hip/hip_fp16.h>

constexpr int IN_FEATS = 30;
constexpr int HIDDEN   = 64;
constexpr int SCAN_CHUNK = 1024;   // elements per scan block (256 thr x 4)
constexpr int RB_BITS = 9;         // 512 nodes per bucket
constexpr int RB_MASK = (1 << RB_BITS) - 1;
constexpr int ECHUNK  = 2048;      // edges per partition block
constexpr int NPB     = 32;        // nodes per transform block
// pair packing: (dstLocal << 23) | src  — requires n < 2^23 (here n = 100000)

// ---- partition pass 1: per-chunk LDS bucket histograms for BOTH dst and src ----
__global__ __launch_bounds__(256) void part_count(
    const int* __restrict__ src, const int* __restrict__ dst,
    int* __restrict__ cntT, int nE, int NBK, int NCH, int NK2)
{
    __shared__ int binsD[256], binsS[256];
    int b = blockIdx.x, t = threadIdx.x;
    binsD[t] = 0; binsS[t] = 0;
    __syncthreads();
    int base = b * ECHUNK;
#pragma unroll
    for (int i = 0; i < ECHUNK / 256; ++i) {
        int e = base + t + i * 256;
        if (e < nE) {
            atomicAdd(&binsD[dst[e] >> RB_BITS], 1);
            atomicAdd(&binsS[src[e] >> RB_BITS], 1);
        }
    }
    __syncthreads();
    if (t < NBK) {
        cntT[t * NCH + b]       = binsD[t];
        cntT[NK2 + t * NCH + b] = binsS[t];
    }
}

// ---- multi-block exclusive scan, phase 1: per-block sums ----
__global__ __launch_bounds__(256) void scan_partial(
    const int* __restrict__ deg, int* __restrict__ blockSum, int n)
{
    __shared__ int part[256];
    int b = blockIdx.x, t = threadIdx.x;
    int base = b * SCAN_CHUNK + t * 4;
    int s = 0;
#pragma unroll
    for (int j = 0; j < 4; ++j) { int i = base + j; if (i < n) s += deg[i]; }
    part[t] = s;
    __syncthreads();
    for (int off = 1; off < 256; off <<= 1) {
        int add = (t >= off) ? part[t - off] : 0;
        __syncthreads();
        part[t] += add;
        __syncthreads();
    }
    if (t == 255) blockSum[b] = part[255];
}

// ---- phase 2: exclusive scan of block sums (1 block; nB <= 1024); optional total ----
__global__ __launch_bounds__(1024) void scan_offsets(int* blockSum, int nB, int* totalPtr)
{
    __shared__ int part[1024];
    int t = threadIdx.x;
    int v = (t < nB) ? blockSum[t] : 0;
    part[t] = v;
    __syncthreads();
    for (int off = 1; off < 1024; off <<= 1) {
        int add = (t >= off) ? part[t - off] : 0;
        __syncthreads();
        part[t] += add;
        __syncthreads();
    }
    if (t < nB) blockSum[t] = part[t] - v;   // exclusive block offset
    if (totalPtr && t == nB - 1) *totalPtr = part[t];
}

// ---- phase 3: rescan chunk, write exclusive start offsets ----
__global__ __launch_bounds__(256) void scan_final(
    const int* __restrict__ deg, const int* __restrict__ blockSum,
    int* __restrict__ outp, int n)
{
    __shared__ int part[256];
    int b = blockIdx.x, t = threadIdx.x;
    int base = b * SCAN_CHUNK + t * 4;
    int v[4];
    int s = 0;
#pragma unroll
    for (int j = 0; j < 4; ++j) { int i = base + j; v[j] = (i < n) ? deg[i] : 0; s += v[j]; }
    part[t] = s;
    __syncthreads();
    for (int off = 1; off < 256; off <<= 1) {
        int add = (t >= off) ? part[t - off] : 0;
        __syncthreads();
        part[t] += add;
        __syncthreads();
    }
    int run = blockSum[b] + part[t] - s;
#pragma unroll
    for (int j = 0; j < 4; ++j) {
        int i = base + j;
        if (i < n) outp[i] = run;
        run += v[j];
    }
}

// ---- dst partition pass 2: LDS counting sort, packed-pair bucket-contiguous write ----
__global__ __launch_bounds__(256) void part_scatter(
    const int* __restrict__ src, const int* __restrict__ dst,
    const int* __restrict__ ofsT, unsigned int* __restrict__ pairs,
    int nE, int NBK, int NCH)
{
    __shared__ int bins[256], lstart[256], lcur[256], gofs[256], part[256];
    __shared__ int lsrc[ECHUNK], ldst[ECHUNK];
    int b = blockIdx.x, t = threadIdx.x;
    bins[t] = 0;
    if (t < NBK) gofs[t] = ofsT[t * NCH + b];
    __syncthreads();
    int base = b * ECHUNK;
    int rs[ECHUNK / 256], rd[ECHUNK / 256];
#pragma unroll
    for (int i = 0; i < ECHUNK / 256; ++i) {
        int e = base + t + i * 256;
        rs[i] = -1;
        if (e < nE) {
            rs[i] = src[e]; rd[i] = dst[e];
            atomicAdd(&bins[rd[i] >> RB_BITS], 1);
        }
    }
    __syncthreads();
    int v = bins[t];
    part[t] = v;
    __syncthreads();
    for (int off = 1; off < 256; off <<= 1) {
        int add = (t >= off) ? part[t - off] : 0;
        __syncthreads();
        part[t] += add;
        __syncthreads();
    }
    lstart[t] = part[t] - v;
    lcur[t]   = part[t] - v;
    __syncthreads();
#pragma unroll
    for (int i = 0; i < ECHUNK / 256; ++i) {
        if (rs[i] >= 0) {
            int k = rd[i] >> RB_BITS;
            int p = atomicAdd(&lcur[k], 1);
            lsrc[p] = rs[i]; ldst[p] = rd[i];
        }
    }
    __syncthreads();
    int cE = min(ECHUNK, nE - base);
    for (int j = t; j < cE; j += 256) {
        int d = ldst[j], k = d >> RB_BITS;
        int g = gofs[k] + (j - lstart[k]);
        pairs[g] = ((unsigned int)(d & RB_MASK) << 23) | (unsigned int)lsrc[j];
    }
}

// ---- src partition scatter (no sort needed): 16-bit local ids, LDS cursors ----
__global__ __launch_bounds__(256) void srcpart_scatter(
    const int* __restrict__ src, const int* __restrict__ ofsT,
    unsigned short* __restrict__ sloc, int nE, int NBK, int NCH, int NK2)
{
    __shared__ int cur[256];
    int b = blockIdx.x, t = threadIdx.x;
    if (t < NBK) cur[t] = ofsT[NK2 + t * NCH + b] - nE;   // src offsets live at [nE..2nE)
    __syncthreads();
    int base = b * ECHUNK;
#pragma unroll
    for (int i = 0; i < ECHUNK / 256; ++i) {
        int e = base + t + i * 256;
        if (e < nE) {
            int s = src[e];
            int pos = atomicAdd(&cur[s >> RB_BITS], 1);
            sloc[pos] = (unsigned short)(s & RB_MASK);
        }
    }
}

// ---- per-bucket degI histogram from packed pairs (zero global atomics) ----
__global__ __launch_bounds__(256) void bucket_histD(
    const unsigned int* __restrict__ pairs, const int* __restrict__ ofsT,
    int* __restrict__ degI, int nE, int n, int NBK, int NCH)
{
    __shared__ int bins[512];
    int k = blockIdx.x, t = threadIdx.x;
    bins[t] = 0; bins[t + 256] = 0;
    __syncthreads();
    int begin = ofsT[k * NCH];
    int end   = (k + 1 < NBK) ? ofsT[(k + 1) * NCH] : nE;
    for (int e = begin + t; e < end; e += 256)
        atomicAdd(&bins[pairs[e] >> 23], 1);
    __syncthreads();
    int base = k << RB_BITS;
    if (base + t < n)       degI[base + t]       = bins[t];
    if (base + 256 + t < n) degI[base + 256 + t] = bins[t + 256];
}

// ---- per-bucket degO histogram from src local ids ----
__global__ __launch_bounds__(256) void bucket_histS(
    const unsigned short* __restrict__ sloc, const int* __restrict__ ofsT,
    int* __restrict__ degO, int nE, int n, int NBK, int NCH, int NK2)
{
    __shared__ int bins[512];
    int k = blockIdx.x, t = threadIdx.x;
    bins[t] = 0; bins[t + 256] = 0;
    __syncthreads();
    int begin = ofsT[NK2 + k * NCH] - nE;
    int end   = (k + 1 < NBK) ? (ofsT[NK2 + (k + 1) * NCH] - nE) : nE;
    for (int e = begin + t; e < end; e += 256)
        atomicAdd(&bins[sloc[e]], 1);
    __syncthreads();
    int base = k << RB_BITS;
    if (base + t < n)       degO[base + t]       = bins[t];
    if (base + 256 + t < n) degO[base + 256 + t] = bins[t + 256];
}

// ---- per-bucket csr placement: LDS cursors, scatter stays L2-resident ----
__global__ __launch_bounds__(256) void csr_place(
    const unsigned int* __restrict__ pairs, const int* __restrict__ ofsT,
    const int* __restrict__ rowptr, int* __restrict__ csr,
    int nE, int n, int NBK, int NCH)
{
    __shared__ int cur[512];
    int k = blockIdx.x, t = threadIdx.x;
    int base = k << RB_BITS;
    int node = base + t;
    cur[t] = (node < n) ? rowptr[node] : 0;
    node += 256;
    cur[t + 256] = (node < n) ? rowptr[node] : 0;
    __syncthreads();
    int begin = ofsT[k * NCH];
    int end   = (k + 1 < NBK) ? ofsT[(k + 1) * NCH] : nE;
    for (int e = begin + t; e < end; e += 256) {
        unsigned int u = pairs[e];
        int p = atomicAdd(&cur[u >> 23], 1);
        csr[p] = (int)(u & 0x7FFFFFu);
    }
}

// ---- precompute xn[u] = fp16(x[u] * out_deg_norm(u)), padded 30->32 feats ----
__global__ __launch_bounds__(256) void xn_prep(
    const float* __restrict__ x, const int* __restrict__ degO,
    unsigned int* __restrict__ xn, int n)
{
    int tid = blockIdx.x * 256 + threadIdx.x;
    int node = tid >> 4, p = tid & 15;
    if (node >= n) return;
    float ns = rsqrtf(fmaxf((float)degO[node], 1.0f));
    float a = (2 * p     < IN_FEATS) ? x[(size_t)node * IN_FEATS + 2 * p]     * ns : 0.0f;
    float b = (2 * p + 1 < IN_FEATS) ? x[(size_t)node * IN_FEATS + 2 * p + 1] * ns : 0.0f;
    __half2 h = __floats2half2_rn(a, b);
    xn[(size_t)node * 16 + p] = *reinterpret_cast<unsigned int*>(&h);
}

// ---- layer-1 aggregation: 8 edge slots/wave, uint2 loads, 2x unroll ----
__global__ __launch_bounds__(256) void gather_x2(
    const unsigned int* __restrict__ xn, const int* __restrict__ csr,
    const int* __restrict__ rowptr, float* __restrict__ aggx, int n)
{
    int wv   = (blockIdx.x * 256 + threadIdx.x) >> 6;
    int lane = threadIdx.x & 63;
    if (wv >= n) return;
    int begin = rowptr[wv], end = rowptr[wv + 1];
    int g = lane >> 3;        // edge slot 0..7
    int p = lane & 7;         // uint2 index (feats 4p..4p+3)
    float a0 = 0, a1 = 0, a2 = 0, a3 = 0;
    int e = begin + g;
    for (; e + 8 < end; e += 16) {
        int s0 = csr[e], s1 = csr[e + 8];
        uint2 u0 = *reinterpret_cast<const uint2*>(xn + (size_t)s0 * 16 + 2 * p);
        uint2 u1 = *reinterpret_cast<const uint2*>(xn + (size_t)s1 * 16 + 2 * p);
        float2 v;
        v = __half22float2(*reinterpret_cast<__half2*>(&u0.x)); a0 += v.x; a1 += v.y;
        v = __half22float2(*reinterpret_cast<__half2*>(&u0.y)); a2 += v.x; a3 += v.y;
        v = __half22float2(*reinterpret_cast<__half2*>(&u1.x)); a0 += v.x; a1 += v.y;
        v = __half22float2(*reinterpret_cast<__half2*>(&u1.y)); a2 += v.x; a3 += v.y;
    }
    if (e < end) {
        int s0 = csr[e];
        uint2 u0 = *reinterpret_cast<const uint2*>(xn + (size_t)s0 * 16 + 2 * p);
        float2 v;
        v = __half22float2(*reinterpret_cast<__half2*>(&u0.x)); a0 += v.x; a1 += v.y;
        v = __half22float2(*reinterpret_cast<__half2*>(&u0.y)); a2 += v.x; a3 += v.y;
    }
    a0 += __shfl_xor(a0, 8);  a1 += __shfl_xor(a1, 8);  a2 += __shfl_xor(a2, 8);  a3 += __shfl_xor(a3, 8);
    a0 += __shfl_xor(a0, 16); a1 += __shfl_xor(a1, 16); a2 += __shfl_xor(a2, 16); a3 += __shfl_xor(a3, 16);
    a0 += __shfl_xor(a0, 32); a1 += __shfl_xor(a1, 32); a2 += __shfl_xor(a2, 32); a3 += __shfl_xor(a3, 32);
    if (g == 0) {
        float4 r = make_float4(a0, a1, a2, a3);
        *reinterpret_cast<float4*>(aggx + (size_t)wv * 32 + 4 * p) = r;
    }
}

// ---- layer-1 dense, register-blocked: 32 nodes/block, 8 acc/thread ----
// h1s[v] = fp16(relu((aggx[v] @ W1) * nd + b1) * ns), packed x2
__global__ __launch_bounds__(256) void transform1(
    const float* __restrict__ aggx, const float* __restrict__ W1,
    const float* __restrict__ b1, const int* __restrict__ degI,
    const int* __restrict__ degO, unsigned int* __restrict__ h1s, int n)
{
    __shared__ float w[32 * HIDDEN];       // 8 KB, rows 30..31 zero
    __shared__ float rows[NPB][32];        // 4 KB
    int t = threadIdx.x;
    int node0 = blockIdx.x * NPB;
    {   // stage W1 (1920 floats = 480 float4) + zero pad to 512 float4
        const float4* w4 = (const float4*)W1;
        float4* lw4 = (float4*)w;
#pragma unroll
        for (int i = 0; i < 2; ++i) {
            int idx = t + 256 * i;
            if (idx < 480)      lw4[idx] = w4[idx];
            else if (idx < 512) lw4[idx] = make_float4(0.f, 0.f, 0.f, 0.f);
        }
    }
    {   // stage rows (32 nodes x 32 floats = 256 float4), 1 per thread
        int node = node0 + (t >> 3);
        if (node < n)
            *reinterpret_cast<float4*>(&rows[t >> 3][(t & 7) * 4]) =
                *reinterpret_cast<const float4*>(aggx + (size_t)node * 32 + (t & 7) * 4);
    }
    __syncthreads();
    int f = t & 63, g = t >> 6;            // g: nodes g*8..g*8+7
    float acc[8] = {0, 0, 0, 0, 0, 0, 0, 0};
#pragma unroll 2
    for (int k = 0; k < 32; k += 4) {
        float w0 = w[(k + 0) * 64 + f], w1 = w[(k + 1) * 64 + f];
        float w2v = w[(k + 2) * 64 + f], w3 = w[(k + 3) * 64 + f];
#pragma unroll
        for (int j = 0; j < 8; ++j) {
            float4 rv = *reinterpret_cast<const float4*>(&rows[g * 8 + j][k]);
            acc[j] = fmaf(rv.x, w0, acc[j]);
            acc[j] = fmaf(rv.y, w1, acc[j]);
            acc[j] = fmaf(rv.z, w2v, acc[j]);
            acc[j] = fmaf(rv.w, w3, acc[j]);
        }
    }
    float bv = b1[f];
#pragma unroll
    for (int j = 0; j < 8; ++j) {
        int node = node0 + g * 8 + j;
        float hv = 0.0f;
        if (node < n) {
            float ndv = rsqrtf(fmaxf((float)degI[node], 1.0f));
            float nsv = rsqrtf(fmaxf((float)degO[node], 1.0f));
            hv = fmaxf(fmaf(acc[j], ndv, bv), 0.0f) * nsv;
        }
        float hv1 = __shfl_down(hv, 1);
        if (node < n && (f & 1) == 0) {
            __half2 h = __floats2half2_rn(hv, hv1);
            h1s[(size_t)node * 32 + (f >> 1)] = *reinterpret_cast<unsigned int*>(&h);
        }
    }
}

// ---- layer-2 aggregation: 4 edge slots/wave, uint2 loads, 2x unroll ----
__global__ __launch_bounds__(256) void gather_h2(
    const unsigned int* __restrict__ h, const int* __restrict__ csr,
    const int* __restrict__ rowptr, float* __restrict__ agg, int n)
{
    int wv   = (blockIdx.x * 256 + threadIdx.x) >> 6;
    int lane = threadIdx.x & 63;
    if (wv >= n) return;
    int begin = rowptr[wv], end = rowptr[wv + 1];
    int g = lane >> 4;        // edge slot 0..3
    int p = lane & 15;        // uint2 index (feats 4p..4p+3)
    float a0 = 0, a1 = 0, a2 = 0, a3 = 0;
    int e = begin + g;
    for (; e + 4 < end; e += 8) {
        int s0 = csr[e], s1 = csr[e + 4];
        uint2 u0 = *reinterpret_cast<const uint2*>(h + (size_t)s0 * 32 + 2 * p);
        uint2 u1 = *reinterpret_cast<const uint2*>(h + (size_t)s1 * 32 + 2 * p);
        float2 v;
        v = __half22float2(*reinterpret_cast<__half2*>(&u0.x)); a0 += v.x; a1 += v.y;
        v = __half22float2(*reinterpret_cast<__half2*>(&u0.y)); a2 += v.x; a3 += v.y;
        v = __half22float2(*reinterpret_cast<__half2*>(&u1.x)); a0 += v.x; a1 += v.y;
        v = __half22float2(*reinterpret_cast<__half2*>(&u1.y)); a2 += v.x; a3 += v.y;
    }
    if (e < end) {
        int s0 = csr[e];
        uint2 u0 = *reinterpret_cast<const uint2*>(h + (size_t)s0 * 32 + 2 * p);
        float2 v;
        v = __half22float2(*reinterpret_cast<__half2*>(&u0.x)); a0 += v.x; a1 += v.y;
        v = __half22float2(*reinterpret_cast<__half2*>(&u0.y)); a2 += v.x; a3 += v.y;
    }
    a0 += __shfl_xor(a0, 16); a1 += __shfl_xor(a1, 16); a2 += __shfl_xor(a2, 16); a3 += __shfl_xor(a3, 16);
    a0 += __shfl_xor(a0, 32); a1 += __shfl_xor(a1, 32); a2 += __shfl_xor(a2, 32); a3 += __shfl_xor(a3, 32);
    if (g == 0) {
        float4 r = make_float4(a0, a1, a2, a3);
        *reinterpret_cast<float4*>(agg + (size_t)wv * 64 + 4 * p) = r;
    }
}

// ---- layer-2 dense, register-blocked, in place on d_out ----
// out[v] = relu((agg[v] @ W2) * nd + b2);  agg == out (rows staged before writes)
__global__ __launch_bounds__(256) void transform2(
    float* aggout, const float* __restrict__ W2,
    const float* __restrict__ b2, const int* __restrict__ degI, int n)
{
    __shared__ float w[HIDDEN * HIDDEN];   // 16 KB
    __shared__ float rows[NPB][HIDDEN];    // 8 KB
    int t = threadIdx.x;
    int node0 = blockIdx.x * NPB;
    {   // stage W2 (4096 floats = 1024 float4), 4 per thread
        const float4* w4 = (const float4*)W2;
        float4* lw4 = (float4*)w;
#pragma unroll
        for (int i = 0; i < 4; ++i) lw4[t + 256 * i] = w4[t + 256 * i];
    }
    {   // stage rows (32 nodes x 64 floats = 512 float4), 2 per thread
#pragma unroll
        for (int i = 0; i < 2; ++i) {
            int idx = t + 256 * i;
            int node = node0 + (idx >> 4);
            if (node < n)
                *reinterpret_cast<float4*>(&rows[idx >> 4][(idx & 15) * 4]) =
                    *reinterpret_cast<const float4*>(aggout + (size_t)node * 64 + (idx & 15) * 4);
        }
    }
    __syncthreads();
    int f = t & 63, g = t >> 6;            // g: nodes g*8..g*8+7
    float acc[8] = {0, 0, 0, 0, 0, 0, 0, 0};
#pragma unroll 2
    for (int k = 0; k < 64; k += 4) {
        float w0 = w[(k + 0) * 64 + f], w1 = w[(k + 1) * 64 + f];
        float w2v = w[(k + 2) * 64 + f], w3 = w[(k + 3) * 64 + f];
#pragma unroll
        for (int j = 0; j < 8; ++j) {
            float4 rv = *reinterpret_cast<const float4*>(&rows[g * 8 + j][k]);
            acc[j] = fmaf(rv.x, w0, acc[j]);
            acc[j] = fmaf(rv.y, w1, acc[j]);
            acc[j] = fmaf(rv.z, w2v, acc[j]);
            acc[j] = fmaf(rv.w, w3, acc[j]);
        }
    }
    float bv = b2[f];
#pragma unroll
    for (int j = 0; j < 8; ++j) {
        int node = node0 + g * 8 + j;
        if (node < n) {
            float ndv = rsqrtf(fmaxf((float)degI[node], 1.0f));
            aggout[(size_t)node * 64 + f] = fmaxf(fmaf(acc[j], ndv, bv), 0.0f);
        }
    }
}

extern "C" void kernel_launch(void* const* d_in, const int* in_sizes, int n_in,
                              void* d_out, int out_size, void* d_ws, size_t ws_size,
                              hipStream_t stream)
{
    const float* x  = (const float*)d_in[0];
    const float* W1 = (const float*)d_in[1];
    const float* b1 = (const float*)d_in[2];
    const float* W2 = (const float*)d_in[3];
    const float* b2 = (const float*)d_in[4];
    const int*  src = (const int*)d_in[5];
    const int*  dst = (const int*)d_in[6];
    float* out = (float*)d_out;

    const int n  = in_sizes[0] / IN_FEATS;   // 100000
    const int nE = in_sizes[5];              // 1200000

    const int NBK = (n + (1 << RB_BITS) - 1) >> RB_BITS;     // 196 buckets (<=256)
    const int NCH = (nE + ECHUNK - 1) / ECHUNK;              // 586 chunks
    const int NK2 = NBK * NCH;

    // workspace: pool FIRST (16B-aligned base) so uint2/float4 loads are aligned.
    //   pool phase A: pairs[nE] | cntT[2*NK2] | bsum[1024] | sloc[nE u16]
    //   pool phase B: xn[n*16 u32] then h1s[n*32 u32]   (phase-A arrays dead)
    // persistent after pool: degO[n] | degI[n] | rowptr[n+1] | csr[nE]
    const size_t poolWords = (size_t)n * 32;
    unsigned int* pairs = (unsigned int*)d_ws;
    int* cntT = (int*)d_ws + nE;
    int* bsum = cntT + 2 * NK2;
    unsigned short* sloc = (unsigned short*)(bsum + 1024);
    unsigned int* xn  = (unsigned int*)d_ws;
    unsigned int* h1s = (unsigned int*)d_ws;
    int* degO   = (int*)d_ws + poolWords;
    int* degI   = degO + n;
    int* rowptr = degI + n;
    int* csr    = rowptr + (n + 1);

    const int nB  = (n + SCAN_CHUNK - 1) / SCAN_CHUNK;           // degI scan blocks
    const int nB2 = (2 * NK2 + SCAN_CHUNK - 1) / SCAN_CHUNK;     // combined cntT scan
    const int waveBlocks = (n * 64 + 255) / 256;
    const int tfBlocks   = (n + NPB - 1) / NPB;

    // combined dst+src bucket counts -> one scan over 2*NK2
    part_count<<<NCH, 256, 0, stream>>>(src, dst, cntT, nE, NBK, NCH, NK2);
    scan_partial<<<nB2, 256, 0, stream>>>(cntT, bsum, 2 * NK2);
    scan_offsets<<<1, 1024, 0, stream>>>(bsum, nB2, nullptr);
    scan_final<<<nB2, 256, 0, stream>>>(cntT, bsum, cntT, 2 * NK2);   // in-place offsets

    // dst partition -> packed pairs; src partition -> 16-bit local ids
    part_scatter<<<NCH, 256, 0, stream>>>(src, dst, cntT, pairs, nE, NBK, NCH);
    srcpart_scatter<<<NCH, 256, 0, stream>>>(src, cntT, sloc, nE, NBK, NCH, NK2);

    // per-bucket LDS histograms (zero global atomics, no memsets needed)
    bucket_histD<<<NBK, 256, 0, stream>>>(pairs, cntT, degI, nE, n, NBK, NCH);
    bucket_histS<<<NBK, 256, 0, stream>>>(sloc, cntT, degO, nE, n, NBK, NCH, NK2);

    // rowptr = exclusive scan of degI; rowptr[n] = nE
    scan_partial<<<nB, 256, 0, stream>>>(degI, bsum, n);
    scan_offsets<<<1, 1024, 0, stream>>>(bsum, nB, rowptr + n);
    scan_final<<<nB, 256, 0, stream>>>(degI, bsum, rowptr, n);
    csr_place<<<NBK, 256, 0, stream>>>(pairs, cntT, rowptr, csr, nE, n, NBK, NCH);

    // layer 1: pack x*ns to fp16 (pool reuse), aggregate into d_out, dense transform
    xn_prep<<<(n * 16 + 255) / 256, 256, 0, stream>>>(x, degO, xn, n);
    gather_x2<<<waveBlocks, 256, 0, stream>>>(xn, csr, rowptr, out /*aggx*/, n);
    transform1<<<tfBlocks, 256, 0, stream>>>(out, W1, b1, degI, degO, h1s, n);

    // layer 2: aggregate h1s into d_out, dense transform in place
    gather_h2<<<waveBlocks, 256, 0, stream>>>(h1s, csr, rowptr, out, n);
    transform2<<<tfBlocks, 256, 0, stream>>>(out, W2, b2, degI, n);
}

// Round 8
// 192.109 us; speedup vs baseline: 11.8754x; 1.0229x over previous
//
#include <hip/hip_runtime.h>
#include <hip/hip_fp16.h>

constexpr int IN_FEATS = 30;
constexpr int HIDDEN   = 64;
constexpr int SCAN_CHUNK = 1024;   // elements per scan block (256 thr x 4)
constexpr int RB_BITS = 9;         // 512 nodes per bucket
constexpr int RB_MASK = (1 << RB_BITS) - 1;
constexpr int ECHUNK  = 2048;      // edges per partition block
constexpr int NPB     = 32;        // nodes per transform block
// pair packing: (dstLocal << 23) | src  — requires n < 2^23 (here n = 100000)

// ---- partition pass 1: per-chunk LDS bucket histograms for BOTH dst and src ----
__global__ __launch_bounds__(256) void part_count(
    const int* __restrict__ src, const int* __restrict__ dst,
    int* __restrict__ cntT, int nE, int NBK, int NCH, int NK2)
{
    __shared__ int binsD[256], binsS[256];
    int b = blockIdx.x, t = threadIdx.x;
    binsD[t] = 0; binsS[t] = 0;
    __syncthreads();
    int base = b * ECHUNK;
#pragma unroll
    for (int i = 0; i < ECHUNK / 256; ++i) {
        int e = base + t + i * 256;
        if (e < nE) {
            atomicAdd(&binsD[dst[e] >> RB_BITS], 1);
            atomicAdd(&binsS[src[e] >> RB_BITS], 1);
        }
    }
    __syncthreads();
    if (t < NBK) {
        cntT[t * NCH + b]       = binsD[t];
        cntT[NK2 + t * NCH + b] = binsS[t];
    }
}

// ---- multi-block exclusive scan, phase 1: per-block sums ----
__global__ __launch_bounds__(256) void scan_partial(
    const int* __restrict__ deg, int* __restrict__ blockSum, int n)
{
    __shared__ int part[256];
    int b = blockIdx.x, t = threadIdx.x;
    int base = b * SCAN_CHUNK + t * 4;
    int s = 0;
#pragma unroll
    for (int j = 0; j < 4; ++j) { int i = base + j; if (i < n) s += deg[i]; }
    part[t] = s;
    __syncthreads();
    for (int off = 1; off < 256; off <<= 1) {
        int add = (t >= off) ? part[t - off] : 0;
        __syncthreads();
        part[t] += add;
        __syncthreads();
    }
    if (t == 255) blockSum[b] = part[255];
}

// ---- phase 2: exclusive scan of block sums (1 block; nB <= 1024) ----
__global__ __launch_bounds__(1024) void scan_offsets(int* blockSum, int nB, int* totalPtr)
{
    __shared__ int part[1024];
    int t = threadIdx.x;
    int v = (t < nB) ? blockSum[t] : 0;
    part[t] = v;
    __syncthreads();
    for (int off = 1; off < 1024; off <<= 1) {
        int add = (t >= off) ? part[t - off] : 0;
        __syncthreads();
        part[t] += add;
        __syncthreads();
    }
    if (t < nB) blockSum[t] = part[t] - v;   // exclusive block offset
    if (totalPtr && t == nB - 1) *totalPtr = part[t];
}

// ---- phase 3: rescan chunk, write exclusive start offsets ----
__global__ __launch_bounds__(256) void scan_final(
    const int* __restrict__ deg, const int* __restrict__ blockSum,
    int* __restrict__ outp, int n)
{
    __shared__ int part[256];
    int b = blockIdx.x, t = threadIdx.x;
    int base = b * SCAN_CHUNK + t * 4;
    int v[4];
    int s = 0;
#pragma unroll
    for (int j = 0; j < 4; ++j) { int i = base + j; v[j] = (i < n) ? deg[i] : 0; s += v[j]; }
    part[t] = s;
    __syncthreads();
    for (int off = 1; off < 256; off <<= 1) {
        int add = (t >= off) ? part[t - off] : 0;
        __syncthreads();
        part[t] += add;
        __syncthreads();
    }
    int run = blockSum[b] + part[t] - s;
#pragma unroll
    for (int j = 0; j < 4; ++j) {
        int i = base + j;
        if (i < n) outp[i] = run;
        run += v[j];
    }
}

// ---- partition pass 2 (merged): dst LDS counting sort -> packed pairs,
//      plus src scatter -> 16-bit local ids. Reads src/dst exactly once. ----
__global__ __launch_bounds__(256) void part_scatter(
    const int* __restrict__ src, const int* __restrict__ dst,
    const int* __restrict__ ofsT, unsigned int* __restrict__ pairs,
    unsigned short* __restrict__ sloc, int nE, int NBK, int NCH, int NK2)
{
    __shared__ int bins[256], lstart[256], lcur[256], gofs[256], part[256], scur[256];
    __shared__ int lsrc[ECHUNK], ldst[ECHUNK];
    int b = blockIdx.x, t = threadIdx.x;
    bins[t] = 0;
    if (t < NBK) {
        gofs[t] = ofsT[t * NCH + b];
        scur[t] = ofsT[NK2 + t * NCH + b] - nE;   // src offsets live at [nE..2nE)
    }
    __syncthreads();
    int base = b * ECHUNK;
    int rs[ECHUNK / 256], rd[ECHUNK / 256];
#pragma unroll
    for (int i = 0; i < ECHUNK / 256; ++i) {
        int e = base + t + i * 256;
        rs[i] = -1;
        if (e < nE) {
            rs[i] = src[e]; rd[i] = dst[e];
            atomicAdd(&bins[rd[i] >> RB_BITS], 1);
        }
    }
    // src-side scatter (independent of dst sort; scur init'd before first sync)
#pragma unroll
    for (int i = 0; i < ECHUNK / 256; ++i) {
        if (rs[i] >= 0) {
            int s = rs[i];
            int pos = atomicAdd(&scur[s >> RB_BITS], 1);
            sloc[pos] = (unsigned short)(s & RB_MASK);
        }
    }
    __syncthreads();
    int v = bins[t];
    part[t] = v;
    __syncthreads();
    for (int off = 1; off < 256; off <<= 1) {
        int add = (t >= off) ? part[t - off] : 0;
        __syncthreads();
        part[t] += add;
        __syncthreads();
    }
    lstart[t] = part[t] - v;
    lcur[t]   = part[t] - v;
    __syncthreads();
#pragma unroll
    for (int i = 0; i < ECHUNK / 256; ++i) {
        if (rs[i] >= 0) {
            int k = rd[i] >> RB_BITS;
            int p = atomicAdd(&lcur[k], 1);
            lsrc[p] = rs[i]; ldst[p] = rd[i];
        }
    }
    __syncthreads();
    int cE = min(ECHUNK, nE - base);
    for (int j = t; j < cE; j += 256) {
        int d = ldst[j], k = d >> RB_BITS;
        int g = gofs[k] + (j - lstart[k]);
        pairs[g] = ((unsigned int)(d & RB_MASK) << 23) | (unsigned int)lsrc[j];
    }
}

// ---- fused dst-side bucket build: hist -> LDS scan -> degI/rowptr -> csr scatter ----
// rowptr[node] = bucketStart + localExclusiveScan  ==  global exclusive scan of degI.
__global__ __launch_bounds__(256) void bucket_build(
    const unsigned int* __restrict__ pairs, const int* __restrict__ ofsT,
    int* __restrict__ degI, int* __restrict__ rowptr, int* __restrict__ csr,
    int nE, int n, int NBK, int NCH)
{
    __shared__ int bins[512];
    __shared__ int part[256];
    __shared__ int cur[512];
    int k = blockIdx.x, t = threadIdx.x;
    bins[t] = 0; bins[t + 256] = 0;
    __syncthreads();
    int begin = ofsT[k * NCH];
    int end   = (k + 1 < NBK) ? ofsT[(k + 1) * NCH] : nE;
    for (int e = begin + t; e < end; e += 256)
        atomicAdd(&bins[pairs[e] >> 23], 1);
    __syncthreads();
    int v0 = bins[2 * t], v1 = bins[2 * t + 1];
    int s = v0 + v1;
    part[t] = s;
    __syncthreads();
    for (int off = 1; off < 256; off <<= 1) {
        int add = (t >= off) ? part[t - off] : 0;
        __syncthreads();
        part[t] += add;
        __syncthreads();
    }
    int pre = part[t] - s;                 // exclusive prefix within bucket
    int base = k << RB_BITS;
    int n0 = base + 2 * t, n1 = n0 + 1;
    int r0 = begin + pre, r1 = r0 + v0;
    cur[2 * t] = r0; cur[2 * t + 1] = r1;
    if (n0 < n) { degI[n0] = v0; rowptr[n0] = r0; }
    if (n1 < n) { degI[n1] = v1; rowptr[n1] = r1; }
    if (k == NBK - 1 && t == 0) rowptr[n] = nE;
    __syncthreads();
    for (int e = begin + t; e < end; e += 256) {
        unsigned int u = pairs[e];
        int p = atomicAdd(&cur[u >> 23], 1);
        csr[p] = (int)(u & 0x7FFFFFu);
    }
}

// ---- fused src-side: degO hist + xn pack (xn[u] = fp16(x[u] * rsqrt(degO)), pad 32) ----
__global__ __launch_bounds__(256) void bucket_srcside(
    const unsigned short* __restrict__ sloc, const int* __restrict__ ofsT,
    const float* __restrict__ x, int* __restrict__ degO,
    unsigned int* __restrict__ xn, int nE, int n, int NBK, int NCH, int NK2)
{
    __shared__ int bins[512];
    int k = blockIdx.x, t = threadIdx.x;
    bins[t] = 0; bins[t + 256] = 0;
    __syncthreads();
    int begin = ofsT[NK2 + k * NCH] - nE;
    int end   = (k + 1 < NBK) ? (ofsT[NK2 + (k + 1) * NCH] - nE) : nE;
    for (int e = begin + t; e < end; e += 256)
        atomicAdd(&bins[sloc[e]], 1);
    __syncthreads();
    int base = k << RB_BITS;
    if (base + t < n)       degO[base + t]       = bins[t];
    if (base + 256 + t < n) degO[base + 256 + t] = bins[t + 256];
    // pack xn for this bucket's nodes: 512 nodes x 16 half2 words
#pragma unroll 4
    for (int i = 0; i < 32; ++i) {
        int idx = t + 256 * i;             // 0..8191
        int nl = idx >> 4, p = idx & 15;
        int node = base + nl;
        if (node < n) {
            float ns = rsqrtf(fmaxf((float)bins[nl], 1.0f));
            float a = (2 * p     < IN_FEATS) ? x[(size_t)node * IN_FEATS + 2 * p]     * ns : 0.0f;
            float b = (2 * p + 1 < IN_FEATS) ? x[(size_t)node * IN_FEATS + 2 * p + 1] * ns : 0.0f;
            __half2 h = __floats2half2_rn(a, b);
            xn[(size_t)node * 16 + p] = *reinterpret_cast<unsigned int*>(&h);
        }
    }
}

// ---- layer-1 aggregation: 8 edge slots/wave, uint2 loads, 2x unroll ----
__global__ __launch_bounds__(256) void gather_x2(
    const unsigned int* __restrict__ xn, const int* __restrict__ csr,
    const int* __restrict__ rowptr, float* __restrict__ aggx, int n)
{
    int wv   = (blockIdx.x * 256 + threadIdx.x) >> 6;
    int lane = threadIdx.x & 63;
    if (wv >= n) return;
    int begin = rowptr[wv], end = rowptr[wv + 1];
    int g = lane >> 3;        // edge slot 0..7
    int p = lane & 7;         // uint2 index (feats 4p..4p+3)
    float a0 = 0, a1 = 0, a2 = 0, a3 = 0;
    int e = begin + g;
    for (; e + 8 < end; e += 16) {
        int s0 = csr[e], s1 = csr[e + 8];
        uint2 u0 = *reinterpret_cast<const uint2*>(xn + (size_t)s0 * 16 + 2 * p);
        uint2 u1 = *reinterpret_cast<const uint2*>(xn + (size_t)s1 * 16 + 2 * p);
        float2 v;
        v = __half22float2(*reinterpret_cast<__half2*>(&u0.x)); a0 += v.x; a1 += v.y;
        v = __half22float2(*reinterpret_cast<__half2*>(&u0.y)); a2 += v.x; a3 += v.y;
        v = __half22float2(*reinterpret_cast<__half2*>(&u1.x)); a0 += v.x; a1 += v.y;
        v = __half22float2(*reinterpret_cast<__half2*>(&u1.y)); a2 += v.x; a3 += v.y;
    }
    if (e < end) {
        int s0 = csr[e];
        uint2 u0 = *reinterpret_cast<const uint2*>(xn + (size_t)s0 * 16 + 2 * p);
        float2 v;
        v = __half22float2(*reinterpret_cast<__half2*>(&u0.x)); a0 += v.x; a1 += v.y;
        v = __half22float2(*reinterpret_cast<__half2*>(&u0.y)); a2 += v.x; a3 += v.y;
    }
    a0 += __shfl_xor(a0, 8);  a1 += __shfl_xor(a1, 8);  a2 += __shfl_xor(a2, 8);  a3 += __shfl_xor(a3, 8);
    a0 += __shfl_xor(a0, 16); a1 += __shfl_xor(a1, 16); a2 += __shfl_xor(a2, 16); a3 += __shfl_xor(a3, 16);
    a0 += __shfl_xor(a0, 32); a1 += __shfl_xor(a1, 32); a2 += __shfl_xor(a2, 32); a3 += __shfl_xor(a3, 32);
    if (g == 0) {
        float4 r = make_float4(a0, a1, a2, a3);
        *reinterpret_cast<float4*>(aggx + (size_t)wv * 32 + 4 * p) = r;
    }
}

// ---- layer-1 dense, register-blocked: 32 nodes/block, 8 acc/thread ----
__global__ __launch_bounds__(256) void transform1(
    const float* __restrict__ aggx, const float* __restrict__ W1,
    const float* __restrict__ b1, const int* __restrict__ degI,
    const int* __restrict__ degO, unsigned int* __restrict__ h1s, int n)
{
    __shared__ float w[32 * HIDDEN];       // 8 KB, rows 30..31 zero
    __shared__ float rows[NPB][32];        // 4 KB
    int t = threadIdx.x;
    int node0 = blockIdx.x * NPB;
    {
        const float4* w4 = (const float4*)W1;
        float4* lw4 = (float4*)w;
#pragma unroll
        for (int i = 0; i < 2; ++i) {
            int idx = t + 256 * i;
            if (idx < 480)      lw4[idx] = w4[idx];
            else if (idx < 512) lw4[idx] = make_float4(0.f, 0.f, 0.f, 0.f);
        }
    }
    {
        int node = node0 + (t >> 3);
        if (node < n)
            *reinterpret_cast<float4*>(&rows[t >> 3][(t & 7) * 4]) =
                *reinterpret_cast<const float4*>(aggx + (size_t)node * 32 + (t & 7) * 4);
    }
    __syncthreads();
    int f = t & 63, g = t >> 6;
    float acc[8] = {0, 0, 0, 0, 0, 0, 0, 0};
#pragma unroll 2
    for (int k = 0; k < 32; k += 4) {
        float w0 = w[(k + 0) * 64 + f], w1 = w[(k + 1) * 64 + f];
        float w2v = w[(k + 2) * 64 + f], w3 = w[(k + 3) * 64 + f];
#pragma unroll
        for (int j = 0; j < 8; ++j) {
            float4 rv = *reinterpret_cast<const float4*>(&rows[g * 8 + j][k]);
            acc[j] = fmaf(rv.x, w0, acc[j]);
            acc[j] = fmaf(rv.y, w1, acc[j]);
            acc[j] = fmaf(rv.z, w2v, acc[j]);
            acc[j] = fmaf(rv.w, w3, acc[j]);
        }
    }
    float bv = b1[f];
#pragma unroll
    for (int j = 0; j < 8; ++j) {
        int node = node0 + g * 8 + j;
        float hv = 0.0f;
        if (node < n) {
            float ndv = rsqrtf(fmaxf((float)degI[node], 1.0f));
            float nsv = rsqrtf(fmaxf((float)degO[node], 1.0f));
            hv = fmaxf(fmaf(acc[j], ndv, bv), 0.0f) * nsv;
        }
        float hv1 = __shfl_down(hv, 1);
        if (node < n && (f & 1) == 0) {
            __half2 h = __floats2half2_rn(hv, hv1);
            h1s[(size_t)node * 32 + (f >> 1)] = *reinterpret_cast<unsigned int*>(&h);
        }
    }
}

// ---- layer-2 aggregation: 4 edge slots/wave, uint2 loads, 2x unroll ----
__global__ __launch_bounds__(256) void gather_h2(
    const unsigned int* __restrict__ h, const int* __restrict__ csr,
    const int* __restrict__ rowptr, float* __restrict__ agg, int n)
{
    int wv   = (blockIdx.x * 256 + threadIdx.x) >> 6;
    int lane = threadIdx.x & 63;
    if (wv >= n) return;
    int begin = rowptr[wv], end = rowptr[wv + 1];
    int g = lane >> 4;        // edge slot 0..3
    int p = lane & 15;        // uint2 index (feats 4p..4p+3)
    float a0 = 0, a1 = 0, a2 = 0, a3 = 0;
    int e = begin + g;
    for (; e + 4 < end; e += 8) {
        int s0 = csr[e], s1 = csr[e + 4];
        uint2 u0 = *reinterpret_cast<const uint2*>(h + (size_t)s0 * 32 + 2 * p);
        uint2 u1 = *reinterpret_cast<const uint2*>(h + (size_t)s1 * 32 + 2 * p);
        float2 v;
        v = __half22float2(*reinterpret_cast<__half2*>(&u0.x)); a0 += v.x; a1 += v.y;
        v = __half22float2(*reinterpret_cast<__half2*>(&u0.y)); a2 += v.x; a3 += v.y;
        v = __half22float2(*reinterpret_cast<__half2*>(&u1.x)); a0 += v.x; a1 += v.y;
        v = __half22float2(*reinterpret_cast<__half2*>(&u1.y)); a2 += v.x; a3 += v.y;
    }
    if (e < end) {
        int s0 = csr[e];
        uint2 u0 = *reinterpret_cast<const uint2*>(h + (size_t)s0 * 32 + 2 * p);
        float2 v;
        v = __half22float2(*reinterpret_cast<__half2*>(&u0.x)); a0 += v.x; a1 += v.y;
        v = __half22float2(*reinterpret_cast<__half2*>(&u0.y)); a2 += v.x; a3 += v.y;
    }
    a0 += __shfl_xor(a0, 16); a1 += __shfl_xor(a1, 16); a2 += __shfl_xor(a2, 16); a3 += __shfl_xor(a3, 16);
    a0 += __shfl_xor(a0, 32); a1 += __shfl_xor(a1, 32); a2 += __shfl_xor(a2, 32); a3 += __shfl_xor(a3, 32);
    if (g == 0) {
        float4 r = make_float4(a0, a1, a2, a3);
        *reinterpret_cast<float4*>(agg + (size_t)wv * 64 + 4 * p) = r;
    }
}

// ---- layer-2 dense, register-blocked, in place on d_out ----
__global__ __launch_bounds__(256) void transform2(
    float* aggout, const float* __restrict__ W2,
    const float* __restrict__ b2, const int* __restrict__ degI, int n)
{
    __shared__ float w[HIDDEN * HIDDEN];   // 16 KB
    __shared__ float rows[NPB][HIDDEN];    // 8 KB
    int t = threadIdx.x;
    int node0 = blockIdx.x * NPB;
    {
        const float4* w4 = (const float4*)W2;
        float4* lw4 = (float4*)w;
#pragma unroll
        for (int i = 0; i < 4; ++i) lw4[t + 256 * i] = w4[t + 256 * i];
    }
    {
#pragma unroll
        for (int i = 0; i < 2; ++i) {
            int idx = t + 256 * i;
            int node = node0 + (idx >> 4);
            if (node < n)
                *reinterpret_cast<float4*>(&rows[idx >> 4][(idx & 15) * 4]) =
                    *reinterpret_cast<const float4*>(aggout + (size_t)node * 64 + (idx & 15) * 4);
        }
    }
    __syncthreads();
    int f = t & 63, g = t >> 6;
    float acc[8] = {0, 0, 0, 0, 0, 0, 0, 0};
#pragma unroll 2
    for (int k = 0; k < 64; k += 4) {
        float w0 = w[(k + 0) * 64 + f], w1 = w[(k + 1) * 64 + f];
        float w2v = w[(k + 2) * 64 + f], w3 = w[(k + 3) * 64 + f];
#pragma unroll
        for (int j = 0; j < 8; ++j) {
            float4 rv = *reinterpret_cast<const float4*>(&rows[g * 8 + j][k]);
            acc[j] = fmaf(rv.x, w0, acc[j]);
            acc[j] = fmaf(rv.y, w1, acc[j]);
            acc[j] = fmaf(rv.z, w2v, acc[j]);
            acc[j] = fmaf(rv.w, w3, acc[j]);
        }
    }
    float bv = b2[f];
#pragma unroll
    for (int j = 0; j < 8; ++j) {
        int node = node0 + g * 8 + j;
        if (node < n) {
            float ndv = rsqrtf(fmaxf((float)degI[node], 1.0f));
            aggout[(size_t)node * 64 + f] = fmaxf(fmaf(acc[j], ndv, bv), 0.0f);
        }
    }
}

extern "C" void kernel_launch(void* const* d_in, const int* in_sizes, int n_in,
                              void* d_out, int out_size, void* d_ws, size_t ws_size,
                              hipStream_t stream)
{
    const float* x  = (const float*)d_in[0];
    const float* W1 = (const float*)d_in[1];
    const float* b1 = (const float*)d_in[2];
    const float* W2 = (const float*)d_in[3];
    const float* b2 = (const float*)d_in[4];
    const int*  src = (const int*)d_in[5];
    const int*  dst = (const int*)d_in[6];
    float* out = (float*)d_out;

    const int n  = in_sizes[0] / IN_FEATS;   // 100000
    const int nE = in_sizes[5];              // 1200000

    const int NBK = (n + (1 << RB_BITS) - 1) >> RB_BITS;     // 196 buckets (<=256)
    const int NCH = (nE + ECHUNK - 1) / ECHUNK;              // 586 chunks
    const int NK2 = NBK * NCH;

    // workspace layout (non-aliased, ~33 MB; ws is plentiful per harness fills):
    // pairs[nE] | cntT[2*NK2] | bsum[1024] | sloc[nE u16] | xn[n*16] | h1s[n*32] |
    // degO[n] | degI[n] | rowptr[n+1] | csr[nE]
    unsigned int* pairs = (unsigned int*)d_ws;
    int* cntT = (int*)d_ws + nE;
    int* bsum = cntT + 2 * NK2;
    unsigned short* sloc = (unsigned short*)(bsum + 1024);
    unsigned int* xn  = (unsigned int*)(bsum + 1024) + (nE + 1) / 2;
    unsigned int* h1s = xn + (size_t)n * 16;
    int* degO   = (int*)(h1s + (size_t)n * 32);
    int* degI   = degO + n;
    int* rowptr = degI + n;
    int* csr    = rowptr + (n + 1);

    const int nB2 = (2 * NK2 + SCAN_CHUNK - 1) / SCAN_CHUNK;     // combined cntT scan
    const int waveBlocks = (n * 64 + 255) / 256;
    const int tfBlocks   = (n + NPB - 1) / NPB;

    // combined dst+src bucket counts -> one scan over 2*NK2 -> in-place offsets
    part_count<<<NCH, 256, 0, stream>>>(src, dst, cntT, nE, NBK, NCH, NK2);
    scan_partial<<<nB2, 256, 0, stream>>>(cntT, bsum, 2 * NK2);
    scan_offsets<<<1, 1024, 0, stream>>>(bsum, nB2, nullptr);
    scan_final<<<nB2, 256, 0, stream>>>(cntT, bsum, cntT, 2 * NK2);

    // single partition pass: packed dst pairs + src local ids
    part_scatter<<<NCH, 256, 0, stream>>>(src, dst, cntT, pairs, sloc, nE, NBK, NCH, NK2);

    // fused bucket kernels: dst side (degI+rowptr+csr), src side (degO+xn)
    bucket_build<<<NBK, 256, 0, stream>>>(pairs, cntT, degI, rowptr, csr, nE, n, NBK, NCH);
    bucket_srcside<<<NBK, 256, 0, stream>>>(sloc, cntT, x, degO, xn, nE, n, NBK, NCH, NK2);

    // layer 1: aggregate xn into d_out (scratch), dense transform -> h1s (fp16)
    gather_x2<<<waveBlocks, 256, 0, stream>>>(xn, csr, rowptr, out /*aggx*/, n);
    transform1<<<tfBlocks, 256, 0, stream>>>(out, W1, b1, degI, degO, h1s, n);

    // layer 2: aggregate h1s into d_out, dense transform in place
    gather_h2<<<waveBlocks, 256, 0, stream>>>(h1s, csr, rowptr, out, n);
    transform2<<<tfBlocks, 256, 0, stream>>>(out, W2, b2, degI, n);
}